// Round 5
// baseline (788.668 us; speedup 1.0000x reference)
//
#include <hip/hip_runtime.h>
#include <math.h>

// ---------------------------------------------------------------------------
// DAHead: B=8, Cin=512, Ci=128, H=W=64, N=4096, Ck=16, NC=19.
// R10: (a) conv1 K-split x2 (grid 2048, 24 waves/CU) -> raw f32 partials in
//      ws[0..64M]; finalize kernel sums + BN + ReLU + hi/lo IN PLACE
//      (element-indexed, race-free; bh/bl use a blocked u16 layout at byte
//      4*i so writes stay inside the owning thread's read window).
//      (b) conv2p+conv2c fused into one dispatch (mode = blockIdx.y>>1) ->
//      2048 blocks, plain/hilo paths interleave on the CUs.
// ws map (MB):
//   0-16  P0 -> bufA (conv1p f32)        16-32 P1 -> bufB (conv1c f32)
//   32-48 C0 -> bh2(blocked) -> vb@32, pam_bf@40
//   48-64 C1 -> bl2(blocked) -> c2h@48, c2l@56
//   16-32 bufD (conv2p out, after cam_feat frees bufB)
//   64-68 wp1,wc1h,wc1l -> egy_part (after conv1)
//   68-68.85 wp2,wc2h,wc2l   69 egy(0.5M)  69.5 qt(1M)  70.5 kt(1M)
// ---------------------------------------------------------------------------

typedef __attribute__((ext_vector_type(8)))  short short8;
typedef __attribute__((ext_vector_type(16))) float f32x16;

__device__ inline unsigned short f2bf(float f) {
    union { float f; unsigned u; } v; v.f = f;
    unsigned r = v.u + 0x7fffu + ((v.u >> 16) & 1u);   // RNE
    return (unsigned short)(r >> 16);
}
__device__ inline float bf2f(unsigned short h) {
    union { unsigned u; float f; } v; v.u = ((unsigned)h) << 16;
    return v.f;
}

// ---- weight prepack: W[co][cin][9] fp32 ->
//      wpack[chunk][tap][g(=ci>>3)][co128][ci8]  (bf16) ----------------------
__global__ __launch_bounds__(256) void wpack_kernel(
    const float* __restrict__ W, unsigned short* __restrict__ wp, int Cin, int total)
{
    int idx = blockIdx.x * 256 + threadIdx.x;
    if (idx >= total) return;
    int chunk = idx / 18432;
    int rem   = idx - chunk * 18432;
    int tap   = rem >> 11;
    int rem2  = rem & 2047;
    int g     = rem2 >> 10;
    int co    = (rem2 >> 3) & 127;
    int ci8   = rem2 & 7;
    int cin   = (chunk << 4) + (g << 3) + ci8;
    wp[idx] = f2bf(W[((size_t)co * Cin + cin) * 9 + tap]);
}

__global__ __launch_bounds__(256) void wpack_split_kernel(
    const float* __restrict__ W, unsigned short* __restrict__ wph,
    unsigned short* __restrict__ wpl, int Cin, int total)
{
    int idx = blockIdx.x * 256 + threadIdx.x;
    if (idx >= total) return;
    int chunk = idx / 18432;
    int rem   = idx - chunk * 18432;
    int tap   = rem >> 11;
    int rem2  = rem & 2047;
    int g     = rem2 >> 10;
    int co    = (rem2 >> 3) & 127;
    int ci8   = rem2 & 7;
    int cin   = (chunk << 4) + (g << 3) + ci8;
    float w = W[((size_t)co * Cin + cin) * 9 + tap];
    unsigned short hi = f2bf(w);
    wph[idx] = hi;
    wpl[idx] = f2bf(w - bf2f(hi));
}

// ---- FUSED conv1, K-split: raw partials out. grid (64, 4, 8), 256 thr -----
// blockIdx.y: bit0 = co-tile (0/64), bit1 = K-half (chunks 0-15 / 16-31).
__global__ __launch_bounds__(256, 4) void conv1_ksplit(
    const float* __restrict__ xin,
    const unsigned short* __restrict__ wpp,
    const unsigned short* __restrict__ wph, const unsigned short* __restrict__ wpl,
    float* __restrict__ partP, float* __restrict__ partC)
{
    const int t   = threadIdx.x;
    const int w2  = t >> 6;           // 0..3
    const int xh  = w2 & 1;           // x half
    const int wy  = w2 >> 1;          // co 32-half
    const int ln  = t & 63;
    const int l31 = ln & 31;
    const int g   = ln >> 5;
    const int y   = blockIdx.x;       // output row
    const int co0 = (blockIdx.y & 1) << 6;
    const int kh  = blockIdx.y >> 1;  // K half
    const int b   = blockIdx.z;

    const int sr   = t >> 6;          // 0..2
    const int sx   = t & 63;
    const int sgy  = y - 1 + sr;
    const bool sv  = (t < 192) && ((unsigned)sgy < 64u);
    const int spid = sr * 66 + sx + 1;

    __shared__ __align__(16) unsigned short Xh[2][3168];   // [buf][g*1584 + pid*8]
    __shared__ __align__(16) unsigned short Xo[2][3168];   // 25344 B total

    for (int i = t; i < 792; i += 256) {
        uint4 z; z.x = 0; z.y = 0; z.z = 0; z.w = 0;
        ((uint4*)Xh)[i] = z;
        ((uint4*)Xo)[i] = z;
    }

    const int co = co0 + (wy << 5) + l31;
    const unsigned short* wPb = wpp + (size_t)(g << 10) + ((size_t)co << 3);
    const unsigned short* wHb = wph + (size_t)(g << 10) + ((size_t)co << 3);
    const unsigned short* wLb = wpl + (size_t)(g << 10) + ((size_t)co << 3);
    const float* xsrc = xin + ((size_t)b << 21) + (((size_t)(kh << 8)) << 12)
                            + (sgy << 6) + sx;

    const f32x16 zero = {0,0,0,0,0,0,0,0,0,0,0,0,0,0,0,0};
    f32x16 ap = zero, ac = zero;

    float xv[16];
    if (sv) {
#pragma unroll
        for (int c = 0; c < 16; c++) xv[c] = xsrc[(size_t)c << 12];
    }
    __syncthreads();   // zero-init done

    if (sv) {
        unsigned short th[16], tl[16];
#pragma unroll
        for (int c = 0; c < 16; c++) {
            unsigned short hi = f2bf(xv[c]);
            th[c] = hi; tl[c] = f2bf(xv[c] - bf2f(hi));
        }
        *(uint4*)&Xh[0][spid << 3]          = ((uint4*)th)[0];
        *(uint4*)&Xh[0][1584 + (spid << 3)] = ((uint4*)th)[1];
        *(uint4*)&Xo[0][spid << 3]          = ((uint4*)tl)[0];
        *(uint4*)&Xo[0][1584 + (spid << 3)] = ((uint4*)tl)[1];
    }

    int cur = 0;
    for (int ch = 0; ch < 16; ++ch) {
        __syncthreads();
        const bool pf = (ch < 15);
        if (pf && sv) {
#pragma unroll
            for (int c = 0; c < 16; c++)
                xv[c] = xsrc[((size_t)(ch + 1) << 16) + ((size_t)c << 12)];
        }
        const size_t wo = (size_t)((kh << 4) + ch) * 18432;
#pragma unroll 3
        for (int tap = 0; tap < 9; ++tap) {
            const int dy = tap / 3, dx = tap - dy * 3;
            const int xi = (g ? 1584 : 0) + (((dy * 66) + (xh << 5) + l31 + dx) << 3);
            short8 vap = *(const short8*)(wPb + wo + tap * 2048);
            short8 vah = *(const short8*)(wHb + wo + tap * 2048);
            short8 val = *(const short8*)(wLb + wo + tap * 2048);
            short8 bh_ = *(const short8*)&Xh[cur][xi];
            short8 bl_ = *(const short8*)&Xo[cur][xi];
            ap = __builtin_amdgcn_mfma_f32_32x32x16_bf16(vap, bh_, ap, 0, 0, 0);
            ac = __builtin_amdgcn_mfma_f32_32x32x16_bf16(vah, bh_, ac, 0, 0, 0);
            ac = __builtin_amdgcn_mfma_f32_32x32x16_bf16(vah, bl_, ac, 0, 0, 0);
            ac = __builtin_amdgcn_mfma_f32_32x32x16_bf16(val, bh_, ac, 0, 0, 0);
        }
        if (pf && sv) {
            unsigned short th[16], tl[16];
#pragma unroll
            for (int c = 0; c < 16; c++) {
                unsigned short hi = f2bf(xv[c]);
                th[c] = hi; tl[c] = f2bf(xv[c] - bf2f(hi));
            }
            const int nb = cur ^ 1;
            *(uint4*)&Xh[nb][spid << 3]          = ((uint4*)th)[0];
            *(uint4*)&Xh[nb][1584 + (spid << 3)] = ((uint4*)th)[1];
            *(uint4*)&Xo[nb][spid << 3]          = ((uint4*)tl)[0];
            *(uint4*)&Xo[nb][1584 + (spid << 3)] = ((uint4*)tl)[1];
        }
        cur ^= 1;
    }

    const int x = (xh << 5) + l31;
    float* pP = partP + (size_t)kh * 4194304;
    float* pC = partC + (size_t)kh * 4194304;
#pragma unroll
    for (int r = 0; r < 16; r++) {
        int c2 = co0 + (wy << 5) + (r & 3) + ((r >> 2) << 3) + (g << 2);
        size_t o = (((size_t)b * 128 + c2) << 12) + (y << 6) + x;
        pP[o] = ap[r];
        pC[o] = ac[r];
    }
}

// ---- conv1 finalize: sum halves + BN + ReLU + hi/lo, fully in place. ------
// NOTE: pointers intentionally NOT __restrict__ (outputs alias inputs;
// each thread only touches its own 8-element window in every region).
// bh2/bl2 use blocked u16 layout: element e -> u16 index (e>>3)*16 + (e&7)
// = 2e for 8-aligned groups (byte 4e, inside the thread's f32 read window).
__global__ __launch_bounds__(256) void conv1_finalize(
    const float* P, const float* C,
    const float* bnp, const float* bnc,
    float* A, float* Bf, unsigned short* bh2, unsigned short* bl2)
{
    const size_t i0 = ((((size_t)blockIdx.x << 8) + threadIdx.x) << 3);
    const int c = (int)((i0 >> 12) & 127);
    const float sp = bnp[c], tp = bnp[128 + c];
    const float sc = bnc[c], tc = bnc[128 + c];

    float p0[8], p1[8], c0[8], c1[8];
    *(float4*)&p0[0] = *(const float4*)(P + i0);
    *(float4*)&p0[4] = *(const float4*)(P + i0 + 4);
    *(float4*)&p1[0] = *(const float4*)(P + 4194304 + i0);
    *(float4*)&p1[4] = *(const float4*)(P + 4194304 + i0 + 4);
    *(float4*)&c0[0] = *(const float4*)(C + i0);
    *(float4*)&c0[4] = *(const float4*)(C + i0 + 4);
    *(float4*)&c1[0] = *(const float4*)(C + 4194304 + i0);
    *(float4*)&c1[4] = *(const float4*)(C + 4194304 + i0 + 4);

    float vp[8], vc[8];
    unsigned short hh[8], ll[8];
#pragma unroll
    for (int k = 0; k < 8; k++) {
        float sP = p0[k] + p1[k];
        float v = fmaf(sP, sp, tp);
        vp[k] = v > 0.f ? v : 0.f;
        float sC = c0[k] + c1[k];
        float w = fmaf(sC, sc, tc);
        w = w > 0.f ? w : 0.f;
        vc[k] = w;
        unsigned short hi = f2bf(w);
        hh[k] = hi;
        ll[k] = f2bf(w - bf2f(hi));
    }
    *(float4*)(A + i0)      = *(float4*)&vp[0];
    *(float4*)(A + i0 + 4)  = *(float4*)&vp[4];
    *(float4*)(Bf + i0)     = *(float4*)&vc[0];
    *(float4*)(Bf + i0 + 4) = *(float4*)&vc[4];
    *(uint4*)(bh2 + (i0 << 1)) = *(uint4*)hh;
    *(uint4*)(bl2 + (i0 << 1)) = *(uint4*)ll;
}

// ---- conv2 combo: plain (pam_bf -> bufD) + hilo (c2h/c2l -> bufA) ---------
// grid (64, 4, 8): blockIdx.y bit0 = co-tile, bit1 = mode (0 plain, 1 hilo).
__global__ __launch_bounds__(256, 4) void conv2_combo(
    const unsigned short* __restrict__ xp,
    const unsigned short* __restrict__ xch, const unsigned short* __restrict__ xcl,
    const unsigned short* __restrict__ wpp, const unsigned short* __restrict__ wph,
    const unsigned short* __restrict__ wpl,
    const float* __restrict__ bnp, const float* __restrict__ bnc,
    float* __restrict__ outP, float* __restrict__ outC)
{
    const int t   = threadIdx.x;
    const int w2  = t >> 6;
    const int xh  = w2 & 1;
    const int wy  = w2 >> 1;
    const int ln  = t & 63;
    const int l31 = ln & 31;
    const int g   = ln >> 5;
    const int y   = blockIdx.x;
    const int mode = blockIdx.y >> 1;
    const int co0  = (blockIdx.y & 1) << 6;
    const int b   = blockIdx.z;

    const int sr   = t >> 6;
    const int sx   = t & 63;
    const int sgy  = y - 1 + sr;
    const bool sv  = (t < 192) && ((unsigned)sgy < 64u);
    const int spid = sr * 66 + sx + 1;

    __shared__ __align__(16) unsigned short Xa[2][3168];
    __shared__ __align__(16) unsigned short Xb[2][3168];   // 25344 B

    for (int i = t; i < 792; i += 256) {
        uint4 z; z.x = 0; z.y = 0; z.z = 0; z.w = 0;
        ((uint4*)Xa)[i] = z;
        ((uint4*)Xb)[i] = z;
    }

    const int co = co0 + (wy << 5) + l31;
    const f32x16 zero = {0,0,0,0,0,0,0,0,0,0,0,0,0,0,0,0};
    f32x16 acc = zero;
    const int x = (xh << 5) + l31;

    if (mode == 0) {
        // ---- plain bf16 conv (conv2p) ----
        const unsigned short* wB = wpp + (size_t)(g << 10) + ((size_t)co << 3);
        const unsigned short* xsrc = xp + ((size_t)b << 19) + (sgy << 6) + sx;

        unsigned short xv[16];
        if (sv) {
#pragma unroll
            for (int c = 0; c < 16; c++) xv[c] = xsrc[(size_t)c << 12];
        }
        __syncthreads();
        if (sv) {
            *(uint4*)&Xa[0][spid << 3]          = ((uint4*)xv)[0];
            *(uint4*)&Xa[0][1584 + (spid << 3)] = ((uint4*)xv)[1];
        }
        int cur = 0;
        for (int ch = 0; ch < 8; ++ch) {
            __syncthreads();
            const bool pf = (ch < 7);
            if (pf && sv) {
#pragma unroll
                for (int c = 0; c < 16; c++)
                    xv[c] = xsrc[((size_t)(ch + 1) << 16) + ((size_t)c << 12)];
            }
            const size_t wo = (size_t)ch * 18432;
#pragma unroll 3
            for (int tap = 0; tap < 9; ++tap) {
                const int dy = tap / 3, dx = tap - dy * 3;
                const int xi = (g ? 1584 : 0) + (((dy * 66) + (xh << 5) + l31 + dx) << 3);
                short8 a  = *(const short8*)(wB + wo + tap * 2048);
                short8 b0 = *(const short8*)&Xa[cur][xi];
                acc = __builtin_amdgcn_mfma_f32_32x32x16_bf16(a, b0, acc, 0, 0, 0);
            }
            if (pf && sv) {
                const int nb = cur ^ 1;
                *(uint4*)&Xa[nb][spid << 3]          = ((uint4*)xv)[0];
                *(uint4*)&Xa[nb][1584 + (spid << 3)] = ((uint4*)xv)[1];
            }
            cur ^= 1;
        }
#pragma unroll
        for (int r = 0; r < 16; r++) {
            int c2 = co0 + (wy << 5) + (r & 3) + ((r >> 2) << 3) + (g << 2);
            float v = fmaf(acc[r], bnp[c2], bnp[128 + c2]);
            v = v > 0.f ? v : 0.f;
            outP[(((size_t)b * 128 + c2) << 12) + (y << 6) + x] = v;
        }
    } else {
        // ---- hilo conv (conv2c) ----
        const unsigned short* wHb = wph + (size_t)(g << 10) + ((size_t)co << 3);
        const unsigned short* wLb = wpl + (size_t)(g << 10) + ((size_t)co << 3);
        const unsigned short* hsrc = xch + ((size_t)b << 19) + (sgy << 6) + sx;
        const unsigned short* lsrc = xcl + ((size_t)b << 19) + (sgy << 6) + sx;

        unsigned short hv[16], lv[16];
        if (sv) {
#pragma unroll
            for (int c = 0; c < 16; c++) {
                hv[c] = hsrc[(size_t)c << 12];
                lv[c] = lsrc[(size_t)c << 12];
            }
        }
        __syncthreads();
        if (sv) {
            *(uint4*)&Xa[0][spid << 3]          = ((uint4*)hv)[0];
            *(uint4*)&Xa[0][1584 + (spid << 3)] = ((uint4*)hv)[1];
            *(uint4*)&Xb[0][spid << 3]          = ((uint4*)lv)[0];
            *(uint4*)&Xb[0][1584 + (spid << 3)] = ((uint4*)lv)[1];
        }
        int cur = 0;
        for (int ch = 0; ch < 8; ++ch) {
            __syncthreads();
            const bool pf = (ch < 7);
            if (pf && sv) {
#pragma unroll
                for (int c = 0; c < 16; c++) {
                    hv[c] = hsrc[((size_t)(ch + 1) << 16) + ((size_t)c << 12)];
                    lv[c] = lsrc[((size_t)(ch + 1) << 16) + ((size_t)c << 12)];
                }
            }
            const size_t wo = (size_t)ch * 18432;
#pragma unroll 3
            for (int tap = 0; tap < 9; ++tap) {
                const int dy = tap / 3, dx = tap - dy * 3;
                const int xi = (g ? 1584 : 0) + (((dy * 66) + (xh << 5) + l31 + dx) << 3);
                short8 ah  = *(const short8*)(wHb + wo + tap * 2048);
                short8 al  = *(const short8*)(wLb + wo + tap * 2048);
                short8 bh_ = *(const short8*)&Xa[cur][xi];
                short8 bl_ = *(const short8*)&Xb[cur][xi];
                acc = __builtin_amdgcn_mfma_f32_32x32x16_bf16(ah, bh_, acc, 0, 0, 0);
                acc = __builtin_amdgcn_mfma_f32_32x32x16_bf16(ah, bl_, acc, 0, 0, 0);
                acc = __builtin_amdgcn_mfma_f32_32x32x16_bf16(al, bh_, acc, 0, 0, 0);
            }
            if (pf && sv) {
                const int nb = cur ^ 1;
                *(uint4*)&Xa[nb][spid << 3]          = ((uint4*)hv)[0];
                *(uint4*)&Xa[nb][1584 + (spid << 3)] = ((uint4*)hv)[1];
                *(uint4*)&Xb[nb][spid << 3]          = ((uint4*)lv)[0];
                *(uint4*)&Xb[nb][1584 + (spid << 3)] = ((uint4*)lv)[1];
            }
            cur ^= 1;
        }
#pragma unroll
        for (int r = 0; r < 16; r++) {
            int c2 = co0 + (wy << 5) + (r & 3) + ((r >> 2) << 3) + (g << 2);
            float v = fmaf(acc[r], bnc[c2], bnc[128 + c2]);
            v = v > 0.f ? v : 0.f;
            outC[(((size_t)b * 128 + c2) << 12) + (y << 6) + x] = v;
        }
    }
}

// ---- CAM Gram via hi/lo MFMA (blocked bh/bl layout). grid (16, 8, 8) ------
__global__ __launch_bounds__(256) void cam_energy_mfma(
    const unsigned short* __restrict__ bh, const unsigned short* __restrict__ bl,
    float* __restrict__ egy_part)
{
    const int t   = threadIdx.x;
    const int w   = t >> 6;
    const int ln  = t & 63;
    const int l31 = ln & 31;
    const int g   = ln >> 5;
    const int i0  = (blockIdx.x >> 2) << 5;
    const int j0  = (blockIdx.x & 3) << 5;
    const int nseg = blockIdx.y;
    const int b   = blockIdx.z;

    __shared__ float red[4][64][17];

    const f32x16 zero = {0,0,0,0,0,0,0,0,0,0,0,0,0,0,0,0};
    f32x16 acc = zero;
    const int nb = (nseg << 9) + (w << 7) + (g << 3);
    // blocked u16 layout: element e -> u16 index 2e (for 8-aligned groups)
    const size_t ri = ((size_t)b * 128 + i0 + l31) << 13;
    const size_t rj = ((size_t)b * 128 + j0 + l31) << 13;

#pragma unroll
    for (int c = 0; c < 8; c++) {
        const int n2 = (nb + (c << 4)) << 1;
        short8 ah  = *(const short8*)(bh + ri + n2);
        short8 al  = *(const short8*)(bl + ri + n2);
        short8 bhf = *(const short8*)(bh + rj + n2);
        short8 blf = *(const short8*)(bl + rj + n2);
        acc = __builtin_amdgcn_mfma_f32_32x32x16_bf16(ah, bhf, acc, 0, 0, 0);
        acc = __builtin_amdgcn_mfma_f32_32x32x16_bf16(ah, blf, acc, 0, 0, 0);
        acc = __builtin_amdgcn_mfma_f32_32x32x16_bf16(al, bhf, acc, 0, 0, 0);
    }
#pragma unroll
    for (int r = 0; r < 16; r++) red[w][ln][r] = acc[r];
    __syncthreads();

    const int lane = t & 63;
    const int rq   = t >> 6;
    float* base = egy_part + (((size_t)(nseg * 8 + b)) << 14);
#pragma unroll
    for (int e = 0; e < 4; e++) {
        const int reg = (rq << 2) + e;
        float v = red[0][lane][reg] + red[1][lane][reg]
                + red[2][lane][reg] + red[3][lane][reg];
        const int i = i0 + (reg & 3) + ((reg >> 2) << 3) + ((lane >> 5) << 2);
        base[i * 128 + j0 + (lane & 31)] = v;
    }
}

// ---- CAM softmax of (rowmax - e), fused 8-seg reduce. grid (8, 8) ---------
__global__ __launch_bounds__(256) void cam_softmax_fused(
    const float* __restrict__ egy_part, float* __restrict__ egy)
{
    const int b   = blockIdx.x;
    const int rg  = blockIdx.y;
    const int t   = threadIdx.x;
    const int row = (rg << 4) + (t >> 4);
    const int jg  = t & 15;

    float e[8];
#pragma unroll
    for (int jj = 0; jj < 8; jj++) e[jj] = 0.f;
    for (int seg = 0; seg < 8; seg++) {
        const float* p = egy_part + (((size_t)(seg * 8 + b)) << 14) + row * 128 + (jg << 3);
#pragma unroll
        for (int jj = 0; jj < 8; jj++) e[jj] += p[jj];
    }
    float mn = e[0];
#pragma unroll
    for (int jj = 1; jj < 8; jj++) mn = fminf(mn, e[jj]);
#pragma unroll
    for (int k = 1; k < 16; k <<= 1) mn = fminf(mn, __shfl_xor(mn, k));
    float s = 0.f;
#pragma unroll
    for (int jj = 0; jj < 8; jj++) { float p = __expf(mn - e[jj]); e[jj] = p; s += p; }
#pragma unroll
    for (int k = 1; k < 16; k <<= 1) s += __shfl_xor(s, k);
    const float inv = 1.f / s;
    float* orow = egy + ((size_t)b << 14) + row * 128 + (jg << 3);
#pragma unroll
    for (int jj = 0; jj < 8; jj++) orow[jj] = e[jj] * inv;
}

// ---- PAM Q/K producer ----
__global__ __launch_bounds__(256) void pam_qk_1x1(
    const float* __restrict__ A, const float* __restrict__ Wb, const float* __restrict__ bb,
    const float* __restrict__ Wc, const float* __restrict__ bc,
    unsigned short* __restrict__ qt, unsigned short* __restrict__ kt)
{
    __shared__ float wl[2 * 16 * 128];
    __shared__ float bl[32];
    const int t = threadIdx.x;
    const int n = (blockIdx.x << 8) + t;
    const int b = blockIdx.y;
    for (int idx = t; idx < 2048; idx += 256) { wl[idx] = Wb[idx]; wl[2048 + idx] = Wc[idx]; }
    if (t < 16) { bl[t] = bb[t]; bl[16 + t] = bc[t]; }
    __syncthreads();
    float ab[16], ac[16];
#pragma unroll
    for (int k = 0; k < 16; k++) { ab[k] = 0.f; ac[k] = 0.f; }
    for (int chn = 0; chn < 128; ++chn) {
        float a = A[(((size_t)b * 128 + chn) << 12) + n];
#pragma unroll
        for (int k = 0; k < 16; k++) {
            ab[k] = fmaf(wl[k * 128 + chn], a, ab[k]);
            ac[k] = fmaf(wl[2048 + k * 128 + chn], a, ac[k]);
        }
    }
    unsigned short uq[16], uk[16];
#pragma unroll
    for (int k = 0; k < 16; k++) {
        uq[k] = f2bf(ab[k] + bl[k]);
        uk[k] = f2bf(ac[k] + bl[16 + k]);
    }
    size_t row = (size_t)b * 4096 + n;
    ((uint4*)qt)[row * 2 + 0] = ((uint4*)uq)[0];
    ((uint4*)qt)[row * 2 + 1] = ((uint4*)uq)[1];
    ((uint4*)kt)[row * 2 + 0] = ((uint4*)uk)[0];
    ((uint4*)kt)[row * 2 + 1] = ((uint4*)uk)[1];
}

// ---- PAM V producer ----
__global__ __launch_bounds__(256) void pam_v_1x1(
    const float* __restrict__ A, const float* __restrict__ Wd, const float* __restrict__ bd,
    unsigned short* __restrict__ vb)
{
    __shared__ float wl[32 * 128];
    __shared__ float bl[32];
    const int t   = threadIdx.x;
    const int n   = (blockIdx.x << 8) + t;
    const int co0 = blockIdx.y << 5;
    const int b   = blockIdx.z;
    for (int idx = t; idx < 4096; idx += 256) {
        int c2 = idx >> 7, chv = idx & 127;
        wl[idx] = Wd[(co0 + c2) * 128 + chv];
    }
    if (t < 32) bl[t] = bd[co0 + t];
    __syncthreads();
    float acc[32];
#pragma unroll
    for (int k = 0; k < 32; k++) acc[k] = 0.f;
    for (int chn = 0; chn < 128; ++chn) {
        float a = A[(((size_t)b * 128 + chn) << 12) + n];
#pragma unroll
        for (int k = 0; k < 32; k++) acc[k] = fmaf(wl[k * 128 + chn], a, acc[k]);
    }
#pragma unroll
    for (int k = 0; k < 32; k++)
        vb[(((size_t)b * 128 + co0 + k) << 12) + n] = f2bf(acc[k] + bl[k]);
}

// ---- PAM attention, MFMA, ONLINE softmax ----------------------------------
__global__ __launch_bounds__(256) void pam_attn_mfma(
    const unsigned short* __restrict__ qt, const unsigned short* __restrict__ kt,
    const unsigned short* __restrict__ vb,
    const float* __restrict__ alpha, const float* __restrict__ Y,
    unsigned short* __restrict__ outb)
{
    const int t  = threadIdx.x;
    const int w  = t >> 6;
    const int L  = t & 63;
    const int ln = L & 31;
    const int g  = L >> 5;
    const int b  = blockIdx.y;
    const int n0 = blockIdx.x << 5;
    const int c0 = w << 5;

    __shared__ unsigned short Pf[16 * 256];
    __shared__ float red[4][32];

    const f32x16 zero = {0,0,0,0,0,0,0,0,0,0,0,0,0,0,0,0};
    short8 qfrag = *(const short8*)(qt + (((size_t)b * 4096 + n0 + ln) << 4) + (g << 3));
    const float al = alpha[0];

    f32x16 acc = zero;
    float rs = 0.f;
    float mold = -3.0e38f;

    for (int m0 = 0; m0 < 4096; m0 += 128) {
        const int mq = m0 + (w << 5);
        short8 kfrag = *(const short8*)(kt + (((size_t)b * 4096 + mq + ln) << 4) + (g << 3));
        f32x16 s = __builtin_amdgcn_mfma_f32_32x32x16_bf16(kfrag, qfrag, zero, 0, 0, 0);

        float lm = s[0];
#pragma unroll
        for (int r = 1; r < 16; r++) lm = fmaxf(lm, s[r]);
        lm = fmaxf(lm, __shfl_xor(lm, 32));
        if (L < 32) red[w][L] = lm;
        __syncthreads();
        const float mb = fmaxf(fmaxf(red[0][ln], red[1][ln]),
                               fmaxf(red[2][ln], red[3][ln]));
        const float mnew = fmaxf(mold, mb);
        const float fs = __expf(mold - mnew);
        mold = mnew;
        rs *= fs;
#pragma unroll
        for (int r = 0; r < 16; r++) acc[r] *= fs;

        float p[16];
#pragma unroll
        for (int r = 0; r < 16; r++) { p[r] = __expf(s[r] - mnew); rs += p[r]; }
        float xx[16];
#pragma unroll
        for (int r = 0; r < 16; r++) xx[r] = __shfl_xor(p[r], 32);

        unsigned short f0[8], f1[8];
#pragma unroll
        for (int i = 0; i < 4; i++) {
            f0[i]     = f2bf(g ? xx[4 + i]  : p[i]);
            f0[4 + i] = f2bf(g ? p[4 + i]   : xx[i]);
            f1[i]     = f2bf(g ? xx[12 + i] : p[8 + i]);
            f1[4 + i] = f2bf(g ? p[12 + i]  : xx[8 + i]);
        }
        *(short8*)(&Pf[((w << 2) + g) * 256 + (ln << 3)])     = *(short8*)f0;
        *(short8*)(&Pf[((w << 2) + 2 + g) * 256 + (ln << 3)]) = *(short8*)f1;
        __syncthreads();

#pragma unroll
        for (int kk = 0; kk < 8; kk++) {
            short8 pfrag = *(const short8*)(&Pf[((kk << 1) + g) * 256 + (ln << 3)]);
            short8 vfrag = *(const short8*)(vb + (((size_t)b * 128 + c0 + ln) << 12)
                                               + m0 + (kk << 4) + (g << 3));
            acc = __builtin_amdgcn_mfma_f32_32x32x16_bf16(vfrag, pfrag, acc, 0, 0, 0);
        }
        __syncthreads();
    }

    rs += __shfl_xor(rs, 32);
    if (L < 32) red[w][L] = rs;
    __syncthreads();
    const float inv = 1.f / (red[0][ln] + red[1][ln] + red[2][ln] + red[3][ln]);
    const int n = n0 + ln;
#pragma unroll
    for (int r = 0; r < 16; r++) {
        int c = c0 + (r & 3) + ((r >> 2) << 3) + (g << 2);
        size_t idx = (((size_t)b * 128 + c) << 12) + n;
        outb[idx] = f2bf(fmaf(al, acc[r] * inv, Y[idx]));
    }
}

// ---- CAM feat: emits hi/lo bf16 directly (feeds conv2c) -------------------
__global__ __launch_bounds__(256) void cam_feat(
    const float* __restrict__ attn, const float* __restrict__ Bf,
    const float* __restrict__ beta, unsigned short* __restrict__ oh,
    unsigned short* __restrict__ ol)
{
    const int t  = threadIdx.x;
    const int n  = (blockIdx.x << 8) + t;
    const int c0 = blockIdx.y << 5;
    const int b  = blockIdx.z;
    __shared__ float al[32 * 128];
    for (int idx = t; idx < 4096; idx += 256)
        al[idx] = attn[(size_t)b * 16384 + (c0 + (idx >> 7)) * 128 + (idx & 127)];
    __syncthreads();
    float acc[32];
#pragma unroll
    for (int k = 0; k < 32; k++) acc[k] = 0.f;
    for (int d = 0; d < 128; ++d) {
        float v = Bf[(((size_t)b * 128 + d) << 12) + n];
#pragma unroll
        for (int k = 0; k < 32; k++) acc[k] = fmaf(al[k * 128 + d], v, acc[k]);
    }
    float be = beta[0];
#pragma unroll
    for (int k = 0; k < 32; k++) {
        size_t idx = (((size_t)b * 128 + c0 + k) << 12) + n;
        float v = fmaf(be, acc[k], Bf[idx]);
        unsigned short hi = f2bf(v);
        oh[idx] = hi;
        ol[idx] = f2bf(v - bf2f(hi));
    }
}

// ---- Final heads ----
__global__ __launch_bounds__(256) void heads(
    const float* __restrict__ FP, const float* __restrict__ FC,
    const float* __restrict__ Wout, const float* __restrict__ bout,
    const float* __restrict__ Wp3, const float* __restrict__ bp3,
    const float* __restrict__ Wc3, const float* __restrict__ bc3,
    float* __restrict__ out)
{
    const int t = threadIdx.x;
    const int n = (blockIdx.x << 8) + t;
    const int b = blockIdx.y;
    __shared__ float wl[3 * 19 * 128];
    __shared__ float bl[3 * 19];
    for (int idx = t; idx < 2432; idx += 256) {
        wl[idx]        = Wout[idx];
        wl[2432 + idx] = Wp3[idx];
        wl[4864 + idx] = Wc3[idx];
    }
    if (t < 19) { bl[t] = bout[t]; bl[19 + t] = bp3[t]; bl[38 + t] = bc3[t]; }
    __syncthreads();
    float am[19], ap[19], ac[19];
#pragma unroll
    for (int o = 0; o < 19; o++) { am[o] = 0.f; ap[o] = 0.f; ac[o] = 0.f; }
    for (int chn = 0; chn < 128; ++chn) {
        float pv = FP[(((size_t)b * 128 + chn) << 12) + n];
        float cv = FC[(((size_t)b * 128 + chn) << 12) + n];
        float fv = pv + cv;
#pragma unroll
        for (int o = 0; o < 19; o++) {
            am[o] = fmaf(wl[o * 128 + chn], fv, am[o]);
            ap[o] = fmaf(wl[2432 + o * 128 + chn], pv, ap[o]);
            ac[o] = fmaf(wl[4864 + o * 128 + chn], cv, ac[o]);
        }
    }
    const size_t OS = (size_t)8 * 19 * 4096;
#pragma unroll
    for (int o = 0; o < 19; o++) {
        size_t base = (((size_t)b * 19 + o) << 12) + n;
        out[base]          = 1.f / (1.f + __expf(-(am[o] + bl[o])));
        out[OS + base]     = 1.f / (1.f + __expf(-(ap[o] + bl[19 + o])));
        out[2 * OS + base] = 1.f / (1.f + __expf(-(ac[o] + bl[38 + o])));
    }
}

extern "C" void kernel_launch(void* const* d_in, const int* in_sizes, int n_in,
                              void* d_out, int out_size, void* d_ws, size_t ws_size,
                              hipStream_t stream)
{
    const float* x     = (const float*)d_in[0];
    const float* Wp1   = (const float*)d_in[1];
    const float* bnp1  = (const float*)d_in[2];
    const float* Wc1   = (const float*)d_in[3];
    const float* bnc1  = (const float*)d_in[4];
    const float* Wb    = (const float*)d_in[5];
    const float* bb    = (const float*)d_in[6];
    const float* Wc    = (const float*)d_in[7];
    const float* bcv   = (const float*)d_in[8];
    const float* Wd    = (const float*)d_in[9];
    const float* bd    = (const float*)d_in[10];
    const float* alpha = (const float*)d_in[11];
    const float* beta  = (const float*)d_in[12];
    const float* Wp2   = (const float*)d_in[13];
    const float* bnp2  = (const float*)d_in[14];
    const float* Wc2   = (const float*)d_in[15];
    const float* bnc2  = (const float*)d_in[16];
    const float* Wout  = (const float*)d_in[17];
    const float* bo    = (const float*)d_in[18];
    const float* Wp3   = (const float*)d_in[19];
    const float* bp3   = (const float*)d_in[20];
    const float* Wc3   = (const float*)d_in[21];
    const float* bc3   = (const float*)d_in[22];
    float* out = (float*)d_out;

    char* ws = (char*)d_ws;
    const size_t MB = 1u << 20;
    const size_t W1 = (size_t)32 * 18432;   // u16 count
    const size_t W2 = (size_t)8 * 18432;

    float*          partP  = (float*)(ws);                 // 0..32M (2 halves)
    float*          partC  = (float*)(ws + 32 * MB);       // 32..64M
    float*          bufA   = (float*)(ws);                 // over P0
    float*          bufB   = (float*)(ws + 16 * MB);       // over P1
    unsigned short* bh2    = (unsigned short*)(ws + 32 * MB);  // blocked, over C0
    unsigned short* bl2    = (unsigned short*)(ws + 48 * MB);  // blocked, over C1
    unsigned short* vb     = (unsigned short*)(ws + 32 * MB);  // after cam_energy
    unsigned short* pam_bf = (unsigned short*)(ws + 40 * MB);
    unsigned short* c2h    = (unsigned short*)(ws + 48 * MB);  // after cam_energy
    unsigned short* c2l    = (unsigned short*)(ws + 56 * MB);
    float*          bufD   = (float*)(ws + 16 * MB);       // conv2p out (after cam_feat)
    unsigned short* wp1    = (unsigned short*)(ws + 64 * MB);
    unsigned short* wc1h   = wp1 + W1;
    unsigned short* wc1l   = wc1h + W1;
    float*          egy_part = (float*)(ws + 64 * MB);     // over conv1 weights (dead)
    unsigned short* wp2    = (unsigned short*)(ws + 68 * MB);
    unsigned short* wc2h   = wp2 + W2;
    unsigned short* wc2l   = wc2h + W2;
    float*          egy    = (float*)(ws + 69 * MB);       // 512KB
    unsigned short* qt     = (unsigned short*)(ws + 69 * MB + (1u << 19));
    unsigned short* kt     = qt + (1u << 19);              // 1MB each

    dim3 blk(256);
    const int n1 = 32 * 18432;
    const int n2 = 8 * 18432;
    wpack_kernel<<<dim3((n1 + 255) / 256), blk, 0, stream>>>(Wp1, wp1, 512, n1);
    wpack_kernel<<<dim3((n2 + 255) / 256), blk, 0, stream>>>(Wp2, wp2, 128, n2);
    wpack_split_kernel<<<dim3((n1 + 255) / 256), blk, 0, stream>>>(Wc1, wc1h, wc1l, 512, n1);
    wpack_split_kernel<<<dim3((n2 + 255) / 256), blk, 0, stream>>>(Wc2, wc2h, wc2l, 128, n2);

    // conv1 (K-split x2) -> partials; finalize -> bufA, bufB, bh2, bl2
    conv1_ksplit<<<dim3(64, 4, 8), blk, 0, stream>>>(x, wp1, wc1h, wc1l, partP, partC);
    conv1_finalize<<<dim3(2048), blk, 0, stream>>>(partP, partC, bnp1, bnc1,
                                                   bufA, bufB, bh2, bl2);
    // CAM Gram + softmax + feat
    cam_energy_mfma<<<dim3(16, 8, 8), blk, 0, stream>>>(bh2, bl2, egy_part);
    cam_softmax_fused<<<dim3(8, 8), blk, 0, stream>>>(egy_part, egy);
    cam_feat<<<dim3(16, 4, 8), blk, 0, stream>>>(egy, bufB, beta, c2h, c2l);
    // PAM
    pam_qk_1x1<<<dim3(16, 8), blk, 0, stream>>>(bufA, Wb, bb, Wc, bcv, qt, kt);
    pam_v_1x1<<<dim3(16, 4, 8), blk, 0, stream>>>(bufA, Wd, bd, vb);
    pam_attn_mfma<<<dim3(128, 8), blk, 0, stream>>>(qt, kt, vb, alpha, bufA, pam_bf);
    // conv2p + conv2c in one dispatch
    conv2_combo<<<dim3(64, 4, 8), blk, 0, stream>>>(pam_bf, c2h, c2l,
                                                    wp2, wc2h, wc2l, bnp2, bnc2,
                                                    bufD, bufA);
    // fusion + heads
    heads<<<dim3(16, 8), blk, 0, stream>>>(bufD, bufA, Wout, bo, Wp3, bp3, Wc3, bc3, out);
}

// Round 6
// 784.592 us; speedup vs baseline: 1.0052x; 1.0052x over previous
//
#include <hip/hip_runtime.h>
#include <math.h>

// ---------------------------------------------------------------------------
// DAHead: B=8, Cin=512, Ci=128, H=W=64, N=4096, Ck=16, NC=19.
// R11: R9 structure (proven 758us) + conv inner-loop load-order fix:
//   vmcnt is IN-ORDER: waiting any load drains all older loads. R8-R10 issued
//   the 16 HBM X-prefetch loads BEFORE the per-tap W loads, so the first W
//   wait of every chunk drained a ~900cyc HBM round trip (MfmaUtil pinned at
//   ~31% across 39/41/47% occupancy). Now: W taps 0-5 issue first (regs),
//   X prefetch issues after (pinned by an asm dep on the address), W taps
//   6-8 issue mid-loop; all W waits keep X in flight; the X wait at chunk
//   end is covered by taps 3-8's MFMAs. Fully unrolled, bit-identical math.
// ws (byte offsets): identical to R9.
//   bufA@0 (16MB fp32)  bufB@16M (16MB fp32)
//   vb@32M (8MB bf16)   egy_part@40M (4MB fp32)   [both dead before conv2p]
//   bufD@32M (16MB fp32, conv2p out)
//   bh@48M, bl@56M (8MB bf16 each) -> pam_bf@48M -> c2h@48M, c2l@56M
//   qt@64M, kt@65M, egy@66M+128K
//   wp1@67M, wc1h, wc1l (1.125MB each), wp2, wc2h, wc2l (288KB each)
// ---------------------------------------------------------------------------

typedef __attribute__((ext_vector_type(8)))  short short8;
typedef __attribute__((ext_vector_type(16))) float f32x16;

__device__ inline unsigned short f2bf(float f) {
    union { float f; unsigned u; } v; v.f = f;
    unsigned r = v.u + 0x7fffu + ((v.u >> 16) & 1u);   // RNE
    return (unsigned short)(r >> 16);
}
__device__ inline float bf2f(unsigned short h) {
    union { unsigned u; float f; } v; v.u = ((unsigned)h) << 16;
    return v.f;
}

// ---- weight prepack: W[co][cin][9] fp32 ->
//      wpack[chunk][tap][g(=ci>>3)][co128][ci8]  (bf16) ----------------------
__global__ __launch_bounds__(256) void wpack_kernel(
    const float* __restrict__ W, unsigned short* __restrict__ wp, int Cin, int total)
{
    int idx = blockIdx.x * 256 + threadIdx.x;
    if (idx >= total) return;
    int chunk = idx / 18432;
    int rem   = idx - chunk * 18432;
    int tap   = rem >> 11;
    int rem2  = rem & 2047;
    int g     = rem2 >> 10;
    int co    = (rem2 >> 3) & 127;
    int ci8   = rem2 & 7;
    int cin   = (chunk << 4) + (g << 3) + ci8;
    wp[idx] = f2bf(W[((size_t)co * Cin + cin) * 9 + tap]);
}

__global__ __launch_bounds__(256) void wpack_split_kernel(
    const float* __restrict__ W, unsigned short* __restrict__ wph,
    unsigned short* __restrict__ wpl, int Cin, int total)
{
    int idx = blockIdx.x * 256 + threadIdx.x;
    if (idx >= total) return;
    int chunk = idx / 18432;
    int rem   = idx - chunk * 18432;
    int tap   = rem >> 11;
    int rem2  = rem & 2047;
    int g     = rem2 >> 10;
    int co    = (rem2 >> 3) & 127;
    int ci8   = rem2 & 7;
    int cin   = (chunk << 4) + (g << 3) + ci8;
    float w = W[((size_t)co * Cin + cin) * 9 + tap];
    unsigned short hi = f2bf(w);
    wph[idx] = hi;
    wpl[idx] = f2bf(w - bf2f(hi));
}

// per-tap MFMA for the merged kernel (bit-identical order to R9)
#define TAPM(T, P_, H_, L_) do {                                              \
    const int xi_ = gofs + ((((T)/3) * 66 + xbase + ((T)%3)) << 3);           \
    short8 bh_ = *(const short8*)&XhL[cur][xi_];                              \
    short8 bl_ = *(const short8*)&XoL[cur][xi_];                              \
    ap = __builtin_amdgcn_mfma_f32_32x32x16_bf16(P_, bh_, ap, 0, 0, 0);       \
    ac = __builtin_amdgcn_mfma_f32_32x32x16_bf16(H_, bh_, ac, 0, 0, 0);       \
    ac = __builtin_amdgcn_mfma_f32_32x32x16_bf16(H_, bl_, ac, 0, 0, 0);       \
    ac = __builtin_amdgcn_mfma_f32_32x32x16_bf16(L_, bh_, ac, 0, 0, 0);       \
} while (0)

// ---- FUSED conv1: plain (Wp1 -> bufA) + hilo (Wc1 -> bufB,bh,bl) ----------
// 256 thr / 4 waves; 1 output row/block; grid (64, 2, 8). LDS 25344 B.
__global__ __launch_bounds__(256, 3) void conv3x3_merged(
    const float* __restrict__ xin,
    const unsigned short* __restrict__ wpp,
    const unsigned short* __restrict__ wph, const unsigned short* __restrict__ wpl,
    const float* __restrict__ bnp, const float* __restrict__ bnc,
    float* __restrict__ outP, float* __restrict__ outC,
    unsigned short* __restrict__ outh, unsigned short* __restrict__ outl)
{
    const int t   = threadIdx.x;
    const int w2  = t >> 6;
    const int xh  = w2 & 1;
    const int wy  = w2 >> 1;
    const int ln  = t & 63;
    const int l31 = ln & 31;
    const int g   = ln >> 5;
    const int y   = blockIdx.x;
    const int co0 = blockIdx.y << 6;
    const int b   = blockIdx.z;

    const int sr   = t >> 6;
    const int sx   = t & 63;
    const int sgy  = y - 1 + sr;
    const bool sv  = (t < 192) && ((unsigned)sgy < 64u);
    const int spid = sr * 66 + sx + 1;

    __shared__ __align__(16) unsigned short XhL[2][3168];
    __shared__ __align__(16) unsigned short XoL[2][3168];   // 25344 B

    for (int i = t; i < 792; i += 256) {
        uint4 z; z.x = 0; z.y = 0; z.z = 0; z.w = 0;
        ((uint4*)XhL)[i] = z;
        ((uint4*)XoL)[i] = z;
    }

    const int co = co0 + (wy << 5) + l31;
    const unsigned short* wPb = wpp + (size_t)(g << 10) + ((size_t)co << 3);
    const unsigned short* wHb = wph + (size_t)(g << 10) + ((size_t)co << 3);
    const unsigned short* wLb = wpl + (size_t)(g << 10) + ((size_t)co << 3);
    const float* xsrc = xin + ((size_t)b << 21) + (sgy << 6) + sx;

    const int gofs  = g ? 1584 : 0;
    const int xbase = (xh << 5) + l31;

    const f32x16 zero = {0,0,0,0,0,0,0,0,0,0,0,0,0,0,0,0};
    f32x16 ap = zero, ac = zero;

    float xv[16];
    if (sv) {
#pragma unroll
        for (int c = 0; c < 16; c++) xv[c] = xsrc[(size_t)c << 12];
    }
    __syncthreads();   // zero-init done

    if (sv) {
        unsigned short th[16], tl[16];
#pragma unroll
        for (int c = 0; c < 16; c++) {
            unsigned short hi = f2bf(xv[c]);
            th[c] = hi; tl[c] = f2bf(xv[c] - bf2f(hi));
        }
        *(uint4*)&XhL[0][spid << 3]          = ((uint4*)th)[0];
        *(uint4*)&XhL[0][1584 + (spid << 3)] = ((uint4*)th)[1];
        *(uint4*)&XoL[0][spid << 3]          = ((uint4*)tl)[0];
        *(uint4*)&XoL[0][1584 + (spid << 3)] = ((uint4*)tl)[1];
    }

    int cur = 0;
    for (int ch = 0; ch < 32; ++ch) {
        __syncthreads();
        const unsigned short* wP = wPb + (size_t)ch * 18432;
        const unsigned short* wH = wHb + (size_t)ch * 18432;
        const unsigned short* wL = wLb + (size_t)ch * 18432;
        // W taps 0-5 issue FIRST (tap-major trios)
        short8 P0 = *(const short8*)(wP);
        short8 H0 = *(const short8*)(wH);
        short8 L0 = *(const short8*)(wL);
        short8 P1 = *(const short8*)(wP + 2048);
        short8 H1 = *(const short8*)(wH + 2048);
        short8 L1 = *(const short8*)(wL + 2048);
        short8 P2 = *(const short8*)(wP + 4096);
        short8 H2 = *(const short8*)(wH + 4096);
        short8 L2 = *(const short8*)(wL + 4096);
        short8 P3 = *(const short8*)(wP + 6144);
        short8 H3 = *(const short8*)(wH + 6144);
        short8 L3 = *(const short8*)(wL + 6144);
        short8 P4 = *(const short8*)(wP + 8192);
        short8 H4 = *(const short8*)(wH + 8192);
        short8 L4 = *(const short8*)(wL + 8192);
        short8 P5 = *(const short8*)(wP + 10240);
        short8 H5 = *(const short8*)(wH + 10240);
        short8 L5 = *(const short8*)(wL + 10240);
        // X prefetch for next chunk — issued AFTER the W loads above; the
        // asm dep on the address keeps the scheduler from hoisting it back.
        const bool pf = (ch < 31);
        if (pf && sv) {
            unsigned long long xa = (unsigned long long)(xsrc + ((size_t)(ch + 1) << 16));
            asm volatile("" : "+v"(xa));
            const float* xs = (const float*)xa;
#pragma unroll
            for (int c = 0; c < 16; c++) xv[c] = xs[(size_t)c << 12];
        }
        // taps 0-2 (W waits leave X in flight: W older than X)
        TAPM(0, P0, H0, L0);
        TAPM(1, P1, H1, L1);
        TAPM(2, P2, H2, L2);
        // W taps 6-8 (issued after X; their wait lands after ~24 MFMAs)
        short8 P6 = *(const short8*)(wP + 12288);
        short8 H6 = *(const short8*)(wH + 12288);
        short8 L6 = *(const short8*)(wL + 12288);
        short8 P7 = *(const short8*)(wP + 14336);
        short8 H7 = *(const short8*)(wH + 14336);
        short8 L7 = *(const short8*)(wL + 14336);
        short8 P8 = *(const short8*)(wP + 16384);
        short8 H8 = *(const short8*)(wH + 16384);
        short8 L8 = *(const short8*)(wL + 16384);
        // taps 3-5
        TAPM(3, P3, H3, L3);
        TAPM(4, P4, H4, L4);
        TAPM(5, P5, H5, L5);
        // taps 6-8
        TAPM(6, P6, H6, L6);
        TAPM(7, P7, H7, L7);
        TAPM(8, P8, H8, L8);
        // stage next chunk (X already returned by now)
        if (pf && sv) {
            unsigned short th[16], tl[16];
#pragma unroll
            for (int c = 0; c < 16; c++) {
                unsigned short hi = f2bf(xv[c]);
                th[c] = hi; tl[c] = f2bf(xv[c] - bf2f(hi));
            }
            const int nb = cur ^ 1;
            *(uint4*)&XhL[nb][spid << 3]          = ((uint4*)th)[0];
            *(uint4*)&XhL[nb][1584 + (spid << 3)] = ((uint4*)th)[1];
            *(uint4*)&XoL[nb][spid << 3]          = ((uint4*)tl)[0];
            *(uint4*)&XoL[nb][1584 + (spid << 3)] = ((uint4*)tl)[1];
        }
        cur ^= 1;
    }

    const int x = xbase;
#pragma unroll
    for (int r = 0; r < 16; r++) {
        int c2 = co0 + (wy << 5) + (r & 3) + ((r >> 2) << 3) + (g << 2);
        size_t o = (((size_t)b * 128 + c2) << 12) + (y << 6) + x;
        float vp = fmaf(ap[r], bnp[c2], bnp[128 + c2]);
        vp = vp > 0.f ? vp : 0.f;
        outP[o] = vp;
        float vc = fmaf(ac[r], bnc[c2], bnc[128 + c2]);
        vc = vc > 0.f ? vc : 0.f;
        outC[o] = vc;
        unsigned short hi = f2bf(vc);
        outh[o] = hi;
        outl[o] = f2bf(vc - bf2f(hi));
    }
}
#undef TAPM

// ---- plain 3x3 conv, bf16 input (conv2p). 256 thr, 1 row. grid (64,2,8) ---
#define TAPP(T, A_) do {                                                      \
    const int xi_ = gofs + ((((T)/3) * 66 + xbase + ((T)%3)) << 3);           \
    short8 b0_ = *(const short8*)&Xl[cur][xi_];                               \
    acc = __builtin_amdgcn_mfma_f32_32x32x16_bf16(A_, b0_, acc, 0, 0, 0);     \
} while (0)

__global__ __launch_bounds__(256, 4) void conv3x3_bf(
    const unsigned short* __restrict__ xin, int Cin,
    const unsigned short* __restrict__ wpk, const float* __restrict__ bn,
    float* __restrict__ out_f32)
{
    const int t   = threadIdx.x;
    const int w2  = t >> 6;
    const int xh  = w2 & 1;
    const int wy  = w2 >> 1;
    const int ln  = t & 63;
    const int l31 = ln & 31;
    const int g   = ln >> 5;
    const int y   = blockIdx.x;
    const int co0 = blockIdx.y << 6;
    const int b   = blockIdx.z;

    const int sr   = t >> 6;
    const int sx   = t & 63;
    const int sgy  = y - 1 + sr;
    const bool sv  = (t < 192) && ((unsigned)sgy < 64u);
    const int spid = sr * 66 + sx + 1;

    __shared__ __align__(16) unsigned short Xl[2][3168];   // 12672 B

    for (int i = t; i < 792; i += 256) {
        uint4 z; z.x = 0; z.y = 0; z.z = 0; z.w = 0;
        ((uint4*)Xl)[i] = z;
    }

    const int co = co0 + (wy << 5) + l31;
    const unsigned short* wB = wpk + (size_t)(g << 10) + ((size_t)co << 3);
    const unsigned short* xsrc = xin + (((size_t)b * Cin) << 12) + (sgy << 6) + sx;

    const int gofs  = g ? 1584 : 0;
    const int xbase = (xh << 5) + l31;

    const f32x16 zero = {0,0,0,0,0,0,0,0,0,0,0,0,0,0,0,0};
    f32x16 acc = zero;

    unsigned short xv[16];
    if (sv) {
#pragma unroll
        for (int c = 0; c < 16; c++) xv[c] = xsrc[(size_t)c << 12];
    }
    __syncthreads();

    if (sv) {
        *(uint4*)&Xl[0][spid << 3]          = ((uint4*)xv)[0];
        *(uint4*)&Xl[0][1584 + (spid << 3)] = ((uint4*)xv)[1];
    }

    const int nchunks = Cin >> 4;
    int cur = 0;
    for (int ch = 0; ch < nchunks; ++ch) {
        __syncthreads();
        const unsigned short* wA = wB + (size_t)ch * 18432;
        // all 9 W taps first
        short8 A0 = *(const short8*)(wA);
        short8 A1 = *(const short8*)(wA + 2048);
        short8 A2 = *(const short8*)(wA + 4096);
        short8 A3 = *(const short8*)(wA + 6144);
        short8 A4 = *(const short8*)(wA + 8192);
        short8 A5 = *(const short8*)(wA + 10240);
        short8 A6 = *(const short8*)(wA + 12288);
        short8 A7 = *(const short8*)(wA + 14336);
        short8 A8 = *(const short8*)(wA + 16384);
        // X prefetch after W
        const bool pf = (ch < nchunks - 1);
        if (pf && sv) {
            unsigned long long xa = (unsigned long long)(xsrc + ((size_t)(ch + 1) << 16));
            asm volatile("" : "+v"(xa));
            const unsigned short* xs = (const unsigned short*)xa;
#pragma unroll
            for (int c = 0; c < 16; c++) xv[c] = xs[(size_t)c << 12];
        }
        TAPP(0, A0); TAPP(1, A1); TAPP(2, A2);
        TAPP(3, A3); TAPP(4, A4); TAPP(5, A5);
        TAPP(6, A6); TAPP(7, A7); TAPP(8, A8);
        if (pf && sv) {
            const int nb = cur ^ 1;
            *(uint4*)&Xl[nb][spid << 3]          = ((uint4*)xv)[0];
            *(uint4*)&Xl[nb][1584 + (spid << 3)] = ((uint4*)xv)[1];
        }
        cur ^= 1;
    }

    const int x = xbase;
#pragma unroll
    for (int r = 0; r < 16; r++) {
        int c2 = co0 + (wy << 5) + (r & 3) + ((r >> 2) << 3) + (g << 2);
        float v = fmaf(acc[r], bn[c2], bn[128 + c2]);
        v = v > 0.f ? v : 0.f;
        out_f32[(((size_t)b * 128 + c2) << 12) + (y << 6) + x] = v;
    }
}
#undef TAPP

// ---- hilo 3x3 conv, pre-split bf16 inputs (conv2c). 256 thr, 1 row. -------
#define TAPH(T, H_, L_) do {                                                  \
    const int xi_ = gofs + ((((T)/3) * 66 + xbase + ((T)%3)) << 3);           \
    short8 bh_ = *(const short8*)&Xa[cur][xi_];                               \
    short8 bl_ = *(const short8*)&Xb[cur][xi_];                               \
    acc = __builtin_amdgcn_mfma_f32_32x32x16_bf16(H_, bh_, acc, 0, 0, 0);     \
    acc = __builtin_amdgcn_mfma_f32_32x32x16_bf16(H_, bl_, acc, 0, 0, 0);     \
    acc = __builtin_amdgcn_mfma_f32_32x32x16_bf16(L_, bh_, acc, 0, 0, 0);     \
} while (0)

__global__ __launch_bounds__(256, 4) void conv3x3_hilo_bf(
    const unsigned short* __restrict__ xhg, const unsigned short* __restrict__ xlg,
    int Cin, const unsigned short* __restrict__ wph, const unsigned short* __restrict__ wpl,
    const float* __restrict__ bn, float* __restrict__ out_f32)
{
    const int t   = threadIdx.x;
    const int w2  = t >> 6;
    const int xh  = w2 & 1;
    const int wy  = w2 >> 1;
    const int ln  = t & 63;
    const int l31 = ln & 31;
    const int g   = ln >> 5;
    const int y   = blockIdx.x;
    const int co0 = blockIdx.y << 6;
    const int b   = blockIdx.z;

    const int sr   = t >> 6;
    const int sx   = t & 63;
    const int sgy  = y - 1 + sr;
    const bool sv  = (t < 192) && ((unsigned)sgy < 64u);
    const int spid = sr * 66 + sx + 1;

    __shared__ __align__(16) unsigned short Xa[2][3168];
    __shared__ __align__(16) unsigned short Xb[2][3168];   // 25344 B

    for (int i = t; i < 792; i += 256) {
        uint4 z; z.x = 0; z.y = 0; z.z = 0; z.w = 0;
        ((uint4*)Xa)[i] = z;
        ((uint4*)Xb)[i] = z;
    }

    const int co = co0 + (wy << 5) + l31;
    const unsigned short* wHb = wph + (size_t)(g << 10) + ((size_t)co << 3);
    const unsigned short* wLb = wpl + (size_t)(g << 10) + ((size_t)co << 3);
    const unsigned short* hsrc = xhg + (((size_t)b * Cin) << 12) + (sgy << 6) + sx;
    const unsigned short* lsrc = xlg + (((size_t)b * Cin) << 12) + (sgy << 6) + sx;

    const int gofs  = g ? 1584 : 0;
    const int xbase = (xh << 5) + l31;

    const f32x16 zero = {0,0,0,0,0,0,0,0,0,0,0,0,0,0,0,0};
    f32x16 acc = zero;

    unsigned short hv[16], lv[16];
    if (sv) {
#pragma unroll
        for (int c = 0; c < 16; c++) { hv[c] = hsrc[(size_t)c << 12]; lv[c] = lsrc[(size_t)c << 12]; }
    }
    __syncthreads();

    if (sv) {
        *(uint4*)&Xa[0][spid << 3]          = ((uint4*)hv)[0];
        *(uint4*)&Xa[0][1584 + (spid << 3)] = ((uint4*)hv)[1];
        *(uint4*)&Xb[0][spid << 3]          = ((uint4*)lv)[0];
        *(uint4*)&Xb[0][1584 + (spid << 3)] = ((uint4*)lv)[1];
    }

    const int nchunks = Cin >> 4;
    int cur = 0;
    for (int ch = 0; ch < nchunks; ++ch) {
        __syncthreads();
        const unsigned short* wH = wHb + (size_t)ch * 18432;
        const unsigned short* wL = wLb + (size_t)ch * 18432;
        // W taps 0-5 first
        short8 H0 = *(const short8*)(wH);
        short8 L0 = *(const short8*)(wL);
        short8 H1 = *(const short8*)(wH + 2048);
        short8 L1 = *(const short8*)(wL + 2048);
        short8 H2 = *(const short8*)(wH + 4096);
        short8 L2 = *(const short8*)(wL + 4096);
        short8 H3 = *(const short8*)(wH + 6144);
        short8 L3 = *(const short8*)(wL + 6144);
        short8 H4 = *(const short8*)(wH + 8192);
        short8 L4 = *(const short8*)(wL + 8192);
        short8 H5 = *(const short8*)(wH + 10240);
        short8 L5 = *(const short8*)(wL + 10240);
        // X prefetch after W
        const bool pf = (ch < nchunks - 1);
        if (pf && sv) {
            unsigned long long ha = (unsigned long long)(hsrc + ((size_t)(ch + 1) << 16));
            unsigned long long la = (unsigned long long)(lsrc + ((size_t)(ch + 1) << 16));
            asm volatile("" : "+v"(ha), "+v"(la));
            const unsigned short* hs = (const unsigned short*)ha;
            const unsigned short* ls = (const unsigned short*)la;
#pragma unroll
            for (int c = 0; c < 16; c++) { hv[c] = hs[(size_t)c << 12]; lv[c] = ls[(size_t)c << 12]; }
        }
        TAPH(0, H0, L0); TAPH(1, H1, L1); TAPH(2, H2, L2);
        // W taps 6-8
        short8 H6 = *(const short8*)(wH + 12288);
        short8 L6 = *(const short8*)(wL + 12288);
        short8 H7 = *(const short8*)(wH + 14336);
        short8 L7 = *(const short8*)(wL + 14336);
        short8 H8 = *(const short8*)(wH + 16384);
        short8 L8 = *(const short8*)(wL + 16384);
        TAPH(3, H3, L3); TAPH(4, H4, L4); TAPH(5, H5, L5);
        TAPH(6, H6, L6); TAPH(7, H7, L7); TAPH(8, H8, L8);
        if (pf && sv) {
            const int nb = cur ^ 1;
            *(uint4*)&Xa[nb][spid << 3]          = ((uint4*)hv)[0];
            *(uint4*)&Xa[nb][1584 + (spid << 3)] = ((uint4*)hv)[1];
            *(uint4*)&Xb[nb][spid << 3]          = ((uint4*)lv)[0];
            *(uint4*)&Xb[nb][1584 + (spid << 3)] = ((uint4*)lv)[1];
        }
        cur ^= 1;
    }

    const int x = xbase;
#pragma unroll
    for (int r = 0; r < 16; r++) {
        int c2 = co0 + (wy << 5) + (r & 3) + ((r >> 2) << 3) + (g << 2);
        float v = fmaf(acc[r], bn[c2], bn[128 + c2]);
        v = v > 0.f ? v : 0.f;
        out_f32[(((size_t)b * 128 + c2) << 12) + (y << 6) + x] = v;
    }
}
#undef TAPH

// ---- CAM Gram via hi/lo MFMA, n-split partials. grid (16, 8, 8) -----------
__global__ __launch_bounds__(256) void cam_energy_mfma(
    const unsigned short* __restrict__ bh, const unsigned short* __restrict__ bl,
    float* __restrict__ egy_part)
{
    const int t   = threadIdx.x;
    const int w   = t >> 6;
    const int ln  = t & 63;
    const int l31 = ln & 31;
    const int g   = ln >> 5;
    const int i0  = (blockIdx.x >> 2) << 5;
    const int j0  = (blockIdx.x & 3) << 5;
    const int nseg = blockIdx.y;
    const int b   = blockIdx.z;

    __shared__ float red[4][64][17];

    const f32x16 zero = {0,0,0,0,0,0,0,0,0,0,0,0,0,0,0,0};
    f32x16 acc = zero;
    const int nb = (nseg << 9) + (w << 7) + (g << 3);
    const size_t ri = ((size_t)b * 128 + i0 + l31) << 12;
    const size_t rj = ((size_t)b * 128 + j0 + l31) << 12;

#pragma unroll
    for (int c = 0; c < 8; c++) {
        const int n0 = nb + (c << 4);
        short8 ah  = *(const short8*)(bh + ri + n0);
        short8 al  = *(const short8*)(bl + ri + n0);
        short8 bhf = *(const short8*)(bh + rj + n0);
        short8 blf = *(const short8*)(bl + rj + n0);
        acc = __builtin_amdgcn_mfma_f32_32x32x16_bf16(ah, bhf, acc, 0, 0, 0);
        acc = __builtin_amdgcn_mfma_f32_32x32x16_bf16(ah, blf, acc, 0, 0, 0);
        acc = __builtin_amdgcn_mfma_f32_32x32x16_bf16(al, bhf, acc, 0, 0, 0);
    }
#pragma unroll
    for (int r = 0; r < 16; r++) red[w][ln][r] = acc[r];
    __syncthreads();

    const int lane = t & 63;
    const int rq   = t >> 6;
    float* base = egy_part + (((size_t)(nseg * 8 + b)) << 14);
#pragma unroll
    for (int e = 0; e < 4; e++) {
        const int reg = (rq << 2) + e;
        float v = red[0][lane][reg] + red[1][lane][reg]
                + red[2][lane][reg] + red[3][lane][reg];
        const int i = i0 + (reg & 3) + ((reg >> 2) << 3) + ((lane >> 5) << 2);
        base[i * 128 + j0 + (lane & 31)] = v;
    }
}

// ---- CAM softmax of (rowmax - e), fused 8-seg reduce. grid (8, 8) ---------
__global__ __launch_bounds__(256) void cam_softmax_fused(
    const float* __restrict__ egy_part, float* __restrict__ egy)
{
    const int b   = blockIdx.x;
    const int rg  = blockIdx.y;
    const int t   = threadIdx.x;
    const int row = (rg << 4) + (t >> 4);
    const int jg  = t & 15;

    float e[8];
#pragma unroll
    for (int jj = 0; jj < 8; jj++) e[jj] = 0.f;
    for (int seg = 0; seg < 8; seg++) {
        const float* p = egy_part + (((size_t)(seg * 8 + b)) << 14) + row * 128 + (jg << 3);
#pragma unroll
        for (int jj = 0; jj < 8; jj++) e[jj] += p[jj];
    }
    float mn = e[0];
#pragma unroll
    for (int jj = 1; jj < 8; jj++) mn = fminf(mn, e[jj]);
#pragma unroll
    for (int k = 1; k < 16; k <<= 1) mn = fminf(mn, __shfl_xor(mn, k));
    float s = 0.f;
#pragma unroll
    for (int jj = 0; jj < 8; jj++) { float p = __expf(mn - e[jj]); e[jj] = p; s += p; }
#pragma unroll
    for (int k = 1; k < 16; k <<= 1) s += __shfl_xor(s, k);
    const float inv = 1.f / s;
    float* orow = egy + ((size_t)b << 14) + row * 128 + (jg << 3);
#pragma unroll
    for (int jj = 0; jj < 8; jj++) orow[jj] = e[jj] * inv;
}

// ---- PAM Q/K producer ----
__global__ __launch_bounds__(256) void pam_qk_1x1(
    const float* __restrict__ A, const float* __restrict__ Wb, const float* __restrict__ bb,
    const float* __restrict__ Wc, const float* __restrict__ bc,
    unsigned short* __restrict__ qt, unsigned short* __restrict__ kt)
{
    __shared__ float wl[2 * 16 * 128];
    __shared__ float bl[32];
    const int t = threadIdx.x;
    const int n = (blockIdx.x << 8) + t;
    const int b = blockIdx.y;
    for (int idx = t; idx < 2048; idx += 256) { wl[idx] = Wb[idx]; wl[2048 + idx] = Wc[idx]; }
    if (t < 16) { bl[t] = bb[t]; bl[16 + t] = bc[t]; }
    __syncthreads();
    float ab[16], ac[16];
#pragma unroll
    for (int k = 0; k < 16; k++) { ab[k] = 0.f; ac[k] = 0.f; }
    for (int chn = 0; chn < 128; ++chn) {
        float a = A[(((size_t)b * 128 + chn) << 12) + n];
#pragma unroll
        for (int k = 0; k < 16; k++) {
            ab[k] = fmaf(wl[k * 128 + chn], a, ab[k]);
            ac[k] = fmaf(wl[2048 + k * 128 + chn], a, ac[k]);
        }
    }
    unsigned short uq[16], uk[16];
#pragma unroll
    for (int k = 0; k < 16; k++) {
        uq[k] = f2bf(ab[k] + bl[k]);
        uk[k] = f2bf(ac[k] + bl[16 + k]);
    }
    size_t row = (size_t)b * 4096 + n;
    ((uint4*)qt)[row * 2 + 0] = ((uint4*)uq)[0];
    ((uint4*)qt)[row * 2 + 1] = ((uint4*)uq)[1];
    ((uint4*)kt)[row * 2 + 0] = ((uint4*)uk)[0];
    ((uint4*)kt)[row * 2 + 1] = ((uint4*)uk)[1];
}

// ---- PAM V producer ----
__global__ __launch_bounds__(256) void pam_v_1x1(
    const float* __restrict__ A, const float* __restrict__ Wd, const float* __restrict__ bd,
    unsigned short* __restrict__ vb)
{
    __shared__ float wl[32 * 128];
    __shared__ float bl[32];
    const int t   = threadIdx.x;
    const int n   = (blockIdx.x << 8) + t;
    const int co0 = blockIdx.y << 5;
    const int b   = blockIdx.z;
    for (int idx = t; idx < 4096; idx += 256) {
        int c2 = idx >> 7, chv = idx & 127;
        wl[idx] = Wd[(co0 + c2) * 128 + chv];
    }
    if (t < 32) bl[t] = bd[co0 + t];
    __syncthreads();
    float acc[32];
#pragma unroll
    for (int k = 0; k < 32; k++) acc[k] = 0.f;
    for (int chn = 0; chn < 128; ++chn) {
        float a = A[(((size_t)b * 128 + chn) << 12) + n];
#pragma unroll
        for (int k = 0; k < 32; k++) acc[k] = fmaf(wl[k * 128 + chn], a, acc[k]);
    }
#pragma unroll
    for (int k = 0; k < 32; k++)
        vb[(((size_t)b * 128 + co0 + k) << 12) + n] = f2bf(acc[k] + bl[k]);
}

// ---- PAM attention, MFMA, ONLINE softmax ----------------------------------
__global__ __launch_bounds__(256) void pam_attn_mfma(
    const unsigned short* __restrict__ qt, const unsigned short* __restrict__ kt,
    const unsigned short* __restrict__ vb,
    const float* __restrict__ alpha, const float* __restrict__ Y,
    unsigned short* __restrict__ outb)
{
    const int t  = threadIdx.x;
    const int w  = t >> 6;
    const int L  = t & 63;
    const int ln = L & 31;
    const int g  = L >> 5;
    const int b  = blockIdx.y;
    const int n0 = blockIdx.x << 5;
    const int c0 = w << 5;

    __shared__ unsigned short Pf[16 * 256];
    __shared__ float red[4][32];

    const f32x16 zero = {0,0,0,0,0,0,0,0,0,0,0,0,0,0,0,0};
    short8 qfrag = *(const short8*)(qt + (((size_t)b * 4096 + n0 + ln) << 4) + (g << 3));
    const float al = alpha[0];

    f32x16 acc = zero;
    float rs = 0.f;
    float mold = -3.0e38f;

    for (int m0 = 0; m0 < 4096; m0 += 128) {
        const int mq = m0 + (w << 5);
        short8 kfrag = *(const short8*)(kt + (((size_t)b * 4096 + mq + ln) << 4) + (g << 3));
        f32x16 s = __builtin_amdgcn_mfma_f32_32x32x16_bf16(kfrag, qfrag, zero, 0, 0, 0);

        float lm = s[0];
#pragma unroll
        for (int r = 1; r < 16; r++) lm = fmaxf(lm, s[r]);
        lm = fmaxf(lm, __shfl_xor(lm, 32));
        if (L < 32) red[w][L] = lm;
        __syncthreads();
        const float mb = fmaxf(fmaxf(red[0][ln], red[1][ln]),
                               fmaxf(red[2][ln], red[3][ln]));
        const float mnew = fmaxf(mold, mb);
        const float fs = __expf(mold - mnew);
        mold = mnew;
        rs *= fs;
#pragma unroll
        for (int r = 0; r < 16; r++) acc[r] *= fs;

        float p[16];
#pragma unroll
        for (int r = 0; r < 16; r++) { p[r] = __expf(s[r] - mnew); rs += p[r]; }
        float xx[16];
#pragma unroll
        for (int r = 0; r < 16; r++) xx[r] = __shfl_xor(p[r], 32);

        unsigned short f0[8], f1[8];
#pragma unroll
        for (int i = 0; i < 4; i++) {
            f0[i]     = f2bf(g ? xx[4 + i]  : p[i]);
            f0[4 + i] = f2bf(g ? p[4 + i]   : xx[i]);
            f1[i]     = f2bf(g ? xx[12 + i] : p[8 + i]);
            f1[4 + i] = f2bf(g ? p[12 + i]  : xx[8 + i]);
        }
        *(short8*)(&Pf[((w << 2) + g) * 256 + (ln << 3)])     = *(short8*)f0;
        *(short8*)(&Pf[((w << 2) + 2 + g) * 256 + (ln << 3)]) = *(short8*)f1;
        __syncthreads();

#pragma unroll
        for (int kk = 0; kk < 8; kk++) {
            short8 pfrag = *(const short8*)(&Pf[((kk << 1) + g) * 256 + (ln << 3)]);
            short8 vfrag = *(const short8*)(vb + (((size_t)b * 128 + c0 + ln) << 12)
                                               + m0 + (kk << 4) + (g << 3));
            acc = __builtin_amdgcn_mfma_f32_32x32x16_bf16(vfrag, pfrag, acc, 0, 0, 0);
        }
        __syncthreads();
    }

    rs += __shfl_xor(rs, 32);
    if (L < 32) red[w][L] = rs;
    __syncthreads();
    const float inv = 1.f / (red[0][ln] + red[1][ln] + red[2][ln] + red[3][ln]);
    const int n = n0 + ln;
#pragma unroll
    for (int r = 0; r < 16; r++) {
        int c = c0 + (r & 3) + ((r >> 2) << 3) + (g << 2);
        size_t idx = (((size_t)b * 128 + c) << 12) + n;
        outb[idx] = f2bf(fmaf(al, acc[r] * inv, Y[idx]));
    }
}

// ---- CAM feat: emits hi/lo bf16 directly (feeds conv2c) -------------------
__global__ __launch_bounds__(256) void cam_feat(
    const float* __restrict__ attn, const float* __restrict__ Bf,
    const float* __restrict__ beta, unsigned short* __restrict__ oh,
    unsigned short* __restrict__ ol)
{
    const int t  = threadIdx.x;
    const int n  = (blockIdx.x << 8) + t;
    const int c0 = blockIdx.y << 5;
    const int b  = blockIdx.z;
    __shared__ float al[32 * 128];
    for (int idx = t; idx < 4096; idx += 256)
        al[idx] = attn[(size_t)b * 16384 + (c0 + (idx >> 7)) * 128 + (idx & 127)];
    __syncthreads();
    float acc[32];
#pragma unroll
    for (int k = 0; k < 32; k++) acc[k] = 0.f;
    for (int d = 0; d < 128; ++d) {
        float v = Bf[(((size_t)b * 128 + d) << 12) + n];
#pragma unroll
        for (int k = 0; k < 32; k++) acc[k] = fmaf(al[k * 128 + d], v, acc[k]);
    }
    float be = beta[0];
#pragma unroll
    for (int k = 0; k < 32; k++) {
        size_t idx = (((size_t)b * 128 + c0 + k) << 12) + n;
        float v = fmaf(be, acc[k], Bf[idx]);
        unsigned short hi = f2bf(v);
        oh[idx] = hi;
        ol[idx] = f2bf(v - bf2f(hi));
    }
}

// ---- Final heads ----
__global__ __launch_bounds__(256) void heads(
    const float* __restrict__ FP, const float* __restrict__ FC,
    const float* __restrict__ Wout, const float* __restrict__ bout,
    const float* __restrict__ Wp3, const float* __restrict__ bp3,
    const float* __restrict__ Wc3, const float* __restrict__ bc3,
    float* __restrict__ out)
{
    const int t = threadIdx.x;
    const int n = (blockIdx.x << 8) + t;
    const int b = blockIdx.y;
    __shared__ float wl[3 * 19 * 128];
    __shared__ float bl[3 * 19];
    for (int idx = t; idx < 2432; idx += 256) {
        wl[idx]        = Wout[idx];
        wl[2432 + idx] = Wp3[idx];
        wl[4864 + idx] = Wc3[idx];
    }
    if (t < 19) { bl[t] = bout[t]; bl[19 + t] = bp3[t]; bl[38 + t] = bc3[t]; }
    __syncthreads();
    float am[19], ap[19], ac[19];
#pragma unroll
    for (int o = 0; o < 19; o++) { am[o] = 0.f; ap[o] = 0.f; ac[o] = 0.f; }
    for (int chn = 0; chn < 128; ++chn) {
        float pv = FP[(((size_t)b * 128 + chn) << 12) + n];
        float cv = FC[(((size_t)b * 128 + chn) << 12) + n];
        float fv = pv + cv;
#pragma unroll
        for (int o = 0; o < 19; o++) {
            am[o] = fmaf(wl[o * 128 + chn], fv, am[o]);
            ap[o] = fmaf(wl[2432 + o * 128 + chn], pv, ap[o]);
            ac[o] = fmaf(wl[4864 + o * 128 + chn], cv, ac[o]);
        }
    }
    const size_t OS = (size_t)8 * 19 * 4096;
#pragma unroll
    for (int o = 0; o < 19; o++) {
        size_t base = (((size_t)b * 19 + o) << 12) + n;
        out[base]          = 1.f / (1.f + __expf(-(am[o] + bl[o])));
        out[OS + base]     = 1.f / (1.f + __expf(-(ap[o] + bl[19 + o])));
        out[2 * OS + base] = 1.f / (1.f + __expf(-(ac[o] + bl[38 + o])));
    }
}

extern "C" void kernel_launch(void* const* d_in, const int* in_sizes, int n_in,
                              void* d_out, int out_size, void* d_ws, size_t ws_size,
                              hipStream_t stream)
{
    const float* x     = (const float*)d_in[0];
    const float* Wp1   = (const float*)d_in[1];
    const float* bnp1  = (const float*)d_in[2];
    const float* Wc1   = (const float*)d_in[3];
    const float* bnc1  = (const float*)d_in[4];
    const float* Wb    = (const float*)d_in[5];
    const float* bb    = (const float*)d_in[6];
    const float* Wc    = (const float*)d_in[7];
    const float* bcv   = (const float*)d_in[8];
    const float* Wd    = (const float*)d_in[9];
    const float* bd    = (const float*)d_in[10];
    const float* alpha = (const float*)d_in[11];
    const float* beta  = (const float*)d_in[12];
    const float* Wp2   = (const float*)d_in[13];
    const float* bnp2  = (const float*)d_in[14];
    const float* Wc2   = (const float*)d_in[15];
    const float* bnc2  = (const float*)d_in[16];
    const float* Wout  = (const float*)d_in[17];
    const float* bo    = (const float*)d_in[18];
    const float* Wp3   = (const float*)d_in[19];
    const float* bp3   = (const float*)d_in[20];
    const float* Wc3   = (const float*)d_in[21];
    const float* bc3   = (const float*)d_in[22];
    float* out = (float*)d_out;

    char* ws = (char*)d_ws;
    const size_t MB = 1u << 20;
    const size_t W1SZ = (size_t)32 * 18432 * 2;
    const size_t W2SZ = (size_t)8 * 18432 * 2;
    float*          bufA     = (float*)(ws);
    float*          bufB     = (float*)(ws + 16 * MB);
    unsigned short* vb       = (unsigned short*)(ws + 32 * MB);  // 8MB
    float*          egy_part = (float*)(ws + 40 * MB);           // 4MB
    float*          bufD     = (float*)(ws + 32 * MB);           // conv2p out (later)
    unsigned short* bh       = (unsigned short*)(ws + 48 * MB);  // 8MB
    unsigned short* blo      = (unsigned short*)(ws + 56 * MB);  // 8MB
    unsigned short* pam_bf   = (unsigned short*)(ws + 48 * MB);  // after Gram
    unsigned short* c2h      = (unsigned short*)(ws + 48 * MB);  // after conv2p
    unsigned short* c2l      = (unsigned short*)(ws + 56 * MB);
    unsigned short* qt       = (unsigned short*)(ws + 64 * MB);
    unsigned short* kt       = (unsigned short*)(ws + 65 * MB);
    float*          egy      = (float*)(ws + 66 * MB + (1u << 17));
    unsigned short* wp1      = (unsigned short*)(ws + 67 * MB);
    unsigned short* wc1h     = (unsigned short*)(ws + 67 * MB + W1SZ);
    unsigned short* wc1l     = (unsigned short*)(ws + 67 * MB + 2 * W1SZ);
    unsigned short* wp2      = (unsigned short*)(ws + 67 * MB + 3 * W1SZ);
    unsigned short* wc2h     = (unsigned short*)(ws + 67 * MB + 3 * W1SZ + W2SZ);
    unsigned short* wc2l     = (unsigned short*)(ws + 67 * MB + 3 * W1SZ + 2 * W2SZ);

    dim3 blk(256);
    const int n1 = 32 * 18432;
    const int n2 = 8 * 18432;
    wpack_kernel<<<dim3((n1 + 255) / 256), blk, 0, stream>>>(Wp1, wp1, 512, n1);
    wpack_kernel<<<dim3((n2 + 255) / 256), blk, 0, stream>>>(Wp2, wp2, 128, n2);
    wpack_split_kernel<<<dim3((n1 + 255) / 256), blk, 0, stream>>>(Wc1, wc1h, wc1l, 512, n1);
    wpack_split_kernel<<<dim3((n2 + 255) / 256), blk, 0, stream>>>(Wc2, wc2h, wc2l, 128, n2);

    // fused conv1p + conv1c (shared hi/lo X staging, dbuf, W in regs, 1-row blocks)
    conv3x3_merged<<<dim3(64, 2, 8), blk, 0, stream>>>(x, wp1, wc1h, wc1l, bnp1, bnc1,
                                                       bufA, bufB, bh, blo);
    // CAM Gram + softmax (consumes bh/bl, egy_part)
    cam_energy_mfma<<<dim3(16, 8, 8), blk, 0, stream>>>(bh, blo, egy_part);
    cam_softmax_fused<<<dim3(8, 8), blk, 0, stream>>>(egy_part, egy);
    // PAM
    pam_qk_1x1<<<dim3(16, 8), blk, 0, stream>>>(bufA, Wb, bb, Wc, bcv, qt, kt);
    pam_v_1x1<<<dim3(16, 4, 8), blk, 0, stream>>>(bufA, Wd, bd, vb);
    pam_attn_mfma<<<dim3(128, 8), blk, 0, stream>>>(qt, kt, vb, alpha, bufA, pam_bf);
    // conv2p (reads pam_bf, writes bufD over vb/egy_part which are now dead)
    conv3x3_bf<<<dim3(64, 2, 8), blk, 0, stream>>>(pam_bf, 128, wp2, bnp2, bufD);
    // CAM tail (c2h/c2l overwrite pam_bf region after conv2p consumed it)
    cam_feat<<<dim3(16, 4, 8), blk, 0, stream>>>(egy, bufB, beta, c2h, c2l);
    conv3x3_hilo_bf<<<dim3(64, 2, 8), blk, 0, stream>>>(c2h, c2l, 128, wc2h, wc2l, bnc2, bufA);
    // fusion + heads
    heads<<<dim3(16, 8), blk, 0, stream>>>(bufD, bufA, Wout, bo, Wp3, bp3, Wc3, bc3, out);
}

// Round 7
// 730.540 us; speedup vs baseline: 1.0796x; 1.0740x over previous
//
#include <hip/hip_runtime.h>
#include <math.h>

// ---------------------------------------------------------------------------
// DAHead: B=8, Cin=512, Ci=128, H=W=64, N=4096, Ck=16, NC=19.
// R12: conv kernels = exact R9 (proven 225us merged / 758 total).
//  (a) pam_attn: Q-tile n0 64 (2 qfrags + 2 accs/wave) -> every vfrag load
//      feeds 2 PV MFMAs, halving V vector-port traffic (1GB -> 0.5GB);
//      Pf/red double-buffered -> 2 barriers/iter instead of 3.
//      Bit-identical per-row softmax math.
//  (b) cam_energy: upper-triangle only (10 tile-pairs vs 16), off-diagonal
//      tiles mirror-written transposed.
// ws (byte offsets): identical to R9.
// ---------------------------------------------------------------------------

typedef __attribute__((ext_vector_type(8)))  short short8;
typedef __attribute__((ext_vector_type(16))) float f32x16;

__device__ inline unsigned short f2bf(float f) {
    union { float f; unsigned u; } v; v.f = f;
    unsigned r = v.u + 0x7fffu + ((v.u >> 16) & 1u);   // RNE
    return (unsigned short)(r >> 16);
}
__device__ inline float bf2f(unsigned short h) {
    union { unsigned u; float f; } v; v.u = ((unsigned)h) << 16;
    return v.f;
}

// ---- weight prepack: W[co][cin][9] fp32 ->
//      wpack[chunk][tap][g(=ci>>3)][co128][ci8]  (bf16) ----------------------
__global__ __launch_bounds__(256) void wpack_kernel(
    const float* __restrict__ W, unsigned short* __restrict__ wp, int Cin, int total)
{
    int idx = blockIdx.x * 256 + threadIdx.x;
    if (idx >= total) return;
    int chunk = idx / 18432;
    int rem   = idx - chunk * 18432;
    int tap   = rem >> 11;
    int rem2  = rem & 2047;
    int g     = rem2 >> 10;
    int co    = (rem2 >> 3) & 127;
    int ci8   = rem2 & 7;
    int cin   = (chunk << 4) + (g << 3) + ci8;
    wp[idx] = f2bf(W[((size_t)co * Cin + cin) * 9 + tap]);
}

__global__ __launch_bounds__(256) void wpack_split_kernel(
    const float* __restrict__ W, unsigned short* __restrict__ wph,
    unsigned short* __restrict__ wpl, int Cin, int total)
{
    int idx = blockIdx.x * 256 + threadIdx.x;
    if (idx >= total) return;
    int chunk = idx / 18432;
    int rem   = idx - chunk * 18432;
    int tap   = rem >> 11;
    int rem2  = rem & 2047;
    int g     = rem2 >> 10;
    int co    = (rem2 >> 3) & 127;
    int ci8   = rem2 & 7;
    int cin   = (chunk << 4) + (g << 3) + ci8;
    float w = W[((size_t)co * Cin + cin) * 9 + tap];
    unsigned short hi = f2bf(w);
    wph[idx] = hi;
    wpl[idx] = f2bf(w - bf2f(hi));
}

// ---- FUSED conv1: plain (Wp1 -> bufA) + hilo (Wc1 -> bufB,bh,bl) ----------
// 256 thr / 4 waves; 1 output row/block; wave tile 32px x 32co.
// grid (64, 2, 8) = 1024 blocks (4/CU). LDS 25344 B.  [exact R9]
__global__ __launch_bounds__(256, 4) void conv3x3_merged(
    const float* __restrict__ xin,
    const unsigned short* __restrict__ wpp,
    const unsigned short* __restrict__ wph, const unsigned short* __restrict__ wpl,
    const float* __restrict__ bnp, const float* __restrict__ bnc,
    float* __restrict__ outP, float* __restrict__ outC,
    unsigned short* __restrict__ outh, unsigned short* __restrict__ outl)
{
    const int t   = threadIdx.x;
    const int w2  = t >> 6;           // 0..3
    const int xh  = w2 & 1;           // x half
    const int wy  = w2 >> 1;          // co 32-half
    const int ln  = t & 63;
    const int l31 = ln & 31;
    const int g   = ln >> 5;
    const int y   = blockIdx.x;       // output row
    const int co0 = blockIdx.y << 6;
    const int b   = blockIdx.z;

    const int sr   = t >> 6;          // 0..2
    const int sx   = t & 63;
    const int sgy  = y - 1 + sr;
    const bool sv  = (t < 192) && ((unsigned)sgy < 64u);
    const int spid = sr * 66 + sx + 1;

    __shared__ __align__(16) unsigned short Xh[2][3168];   // [buf][g*1584 + pid*8]
    __shared__ __align__(16) unsigned short Xo[2][3168];   // 25344 B total

    for (int i = t; i < 792; i += 256) {
        uint4 z; z.x = 0; z.y = 0; z.z = 0; z.w = 0;
        ((uint4*)Xh)[i] = z;
        ((uint4*)Xo)[i] = z;
    }

    const int co = co0 + (wy << 5) + l31;
    const unsigned short* wPb = wpp + (size_t)(g << 10) + ((size_t)co << 3);
    const unsigned short* wHb = wph + (size_t)(g << 10) + ((size_t)co << 3);
    const unsigned short* wLb = wpl + (size_t)(g << 10) + ((size_t)co << 3);
    const float* xsrc = xin + ((size_t)b << 21) + (sgy << 6) + sx;

    const f32x16 zero = {0,0,0,0,0,0,0,0,0,0,0,0,0,0,0,0};
    f32x16 ap = zero, ac = zero;

    float xv[16];
    if (sv) {
#pragma unroll
        for (int c = 0; c < 16; c++) xv[c] = xsrc[(size_t)c << 12];
    }
    __syncthreads();   // zero-init done

    if (sv) {
        unsigned short th[16], tl[16];
#pragma unroll
        for (int c = 0; c < 16; c++) {
            unsigned short hi = f2bf(xv[c]);
            th[c] = hi; tl[c] = f2bf(xv[c] - bf2f(hi));
        }
        *(uint4*)&Xh[0][spid << 3]          = ((uint4*)th)[0];
        *(uint4*)&Xh[0][1584 + (spid << 3)] = ((uint4*)th)[1];
        *(uint4*)&Xo[0][spid << 3]          = ((uint4*)tl)[0];
        *(uint4*)&Xo[0][1584 + (spid << 3)] = ((uint4*)tl)[1];
    }

    int cur = 0;
    for (int ch = 0; ch < 32; ++ch) {
        __syncthreads();
        const bool pf = (ch < 31);
        if (pf && sv) {
#pragma unroll
            for (int c = 0; c < 16; c++)
                xv[c] = xsrc[((size_t)(ch + 1) << 16) + ((size_t)c << 12)];
        }
        const size_t wo = (size_t)ch * 18432;
#pragma unroll 3
        for (int tap = 0; tap < 9; ++tap) {
            const int dy = tap / 3, dx = tap - dy * 3;
            const int xi = (g ? 1584 : 0) + (((dy * 66) + (xh << 5) + l31 + dx) << 3);
            short8 vap = *(const short8*)(wPb + wo + tap * 2048);
            short8 vah = *(const short8*)(wHb + wo + tap * 2048);
            short8 val = *(const short8*)(wLb + wo + tap * 2048);
            short8 bh_ = *(const short8*)&Xh[cur][xi];
            short8 bl_ = *(const short8*)&Xo[cur][xi];
            ap = __builtin_amdgcn_mfma_f32_32x32x16_bf16(vap, bh_, ap, 0, 0, 0);
            ac = __builtin_amdgcn_mfma_f32_32x32x16_bf16(vah, bh_, ac, 0, 0, 0);
            ac = __builtin_amdgcn_mfma_f32_32x32x16_bf16(vah, bl_, ac, 0, 0, 0);
            ac = __builtin_amdgcn_mfma_f32_32x32x16_bf16(val, bh_, ac, 0, 0, 0);
        }
        if (pf && sv) {
            unsigned short th[16], tl[16];
#pragma unroll
            for (int c = 0; c < 16; c++) {
                unsigned short hi = f2bf(xv[c]);
                th[c] = hi; tl[c] = f2bf(xv[c] - bf2f(hi));
            }
            const int nb = cur ^ 1;
            *(uint4*)&Xh[nb][spid << 3]          = ((uint4*)th)[0];
            *(uint4*)&Xh[nb][1584 + (spid << 3)] = ((uint4*)th)[1];
            *(uint4*)&Xo[nb][spid << 3]          = ((uint4*)tl)[0];
            *(uint4*)&Xo[nb][1584 + (spid << 3)] = ((uint4*)tl)[1];
        }
        cur ^= 1;
    }

    const int x = (xh << 5) + l31;
#pragma unroll
    for (int r = 0; r < 16; r++) {
        int c2 = co0 + (wy << 5) + (r & 3) + ((r >> 2) << 3) + (g << 2);
        size_t o = (((size_t)b * 128 + c2) << 12) + (y << 6) + x;
        float vp = fmaf(ap[r], bnp[c2], bnp[128 + c2]);
        vp = vp > 0.f ? vp : 0.f;
        outP[o] = vp;
        float vc = fmaf(ac[r], bnc[c2], bnc[128 + c2]);
        vc = vc > 0.f ? vc : 0.f;
        outC[o] = vc;
        unsigned short hi = f2bf(vc);
        outh[o] = hi;
        outl[o] = f2bf(vc - bf2f(hi));
    }
}

// ---- plain 3x3 conv, bf16 input (conv2p). 256 thr, 1 row. grid (64,2,8) ---
__global__ __launch_bounds__(256, 4) void conv3x3_bf(
    const unsigned short* __restrict__ xin, int Cin,
    const unsigned short* __restrict__ wpk, const float* __restrict__ bn,
    float* __restrict__ out_f32)
{
    const int t   = threadIdx.x;
    const int w2  = t >> 6;
    const int xh  = w2 & 1;
    const int wy  = w2 >> 1;
    const int ln  = t & 63;
    const int l31 = ln & 31;
    const int g   = ln >> 5;
    const int y   = blockIdx.x;
    const int co0 = blockIdx.y << 6;
    const int b   = blockIdx.z;

    const int sr   = t >> 6;
    const int sx   = t & 63;
    const int sgy  = y - 1 + sr;
    const bool sv  = (t < 192) && ((unsigned)sgy < 64u);
    const int spid = sr * 66 + sx + 1;

    __shared__ __align__(16) unsigned short Xl[2][3168];   // 12672 B

    for (int i = t; i < 792; i += 256) {
        uint4 z; z.x = 0; z.y = 0; z.z = 0; z.w = 0;
        ((uint4*)Xl)[i] = z;
    }

    const int co = co0 + (wy << 5) + l31;
    const unsigned short* wB = wpk + (size_t)(g << 10) + ((size_t)co << 3);
    const unsigned short* xsrc = xin + (((size_t)b * Cin) << 12) + (sgy << 6) + sx;

    const f32x16 zero = {0,0,0,0,0,0,0,0,0,0,0,0,0,0,0,0};
    f32x16 acc = zero;

    unsigned short xv[16];
    if (sv) {
#pragma unroll
        for (int c = 0; c < 16; c++) xv[c] = xsrc[(size_t)c << 12];
    }
    __syncthreads();

    if (sv) {
        *(uint4*)&Xl[0][spid << 3]          = ((uint4*)xv)[0];
        *(uint4*)&Xl[0][1584 + (spid << 3)] = ((uint4*)xv)[1];
    }

    const int nchunks = Cin >> 4;
    int cur = 0;
    for (int ch = 0; ch < nchunks; ++ch) {
        __syncthreads();
        const bool pf = (ch < nchunks - 1);
        if (pf && sv) {
#pragma unroll
            for (int c = 0; c < 16; c++)
                xv[c] = xsrc[((size_t)(ch + 1) << 16) + ((size_t)c << 12)];
        }
        const size_t wo = (size_t)ch * 18432;
#pragma unroll 3
        for (int tap = 0; tap < 9; ++tap) {
            const int dy = tap / 3, dx = tap - dy * 3;
            const int xi = (g ? 1584 : 0) + (((dy * 66) + (xh << 5) + l31 + dx) << 3);
            short8 a  = *(const short8*)(wB + wo + tap * 2048);
            short8 b0 = *(const short8*)&Xl[cur][xi];
            acc = __builtin_amdgcn_mfma_f32_32x32x16_bf16(a, b0, acc, 0, 0, 0);
        }
        if (pf && sv) {
            const int nb = cur ^ 1;
            *(uint4*)&Xl[nb][spid << 3]          = ((uint4*)xv)[0];
            *(uint4*)&Xl[nb][1584 + (spid << 3)] = ((uint4*)xv)[1];
        }
        cur ^= 1;
    }

    const int x = (xh << 5) + l31;
#pragma unroll
    for (int r = 0; r < 16; r++) {
        int c2 = co0 + (wy << 5) + (r & 3) + ((r >> 2) << 3) + (g << 2);
        float v = fmaf(acc[r], bn[c2], bn[128 + c2]);
        v = v > 0.f ? v : 0.f;
        out_f32[(((size_t)b * 128 + c2) << 12) + (y << 6) + x] = v;
    }
}

// ---- hilo 3x3 conv, pre-split bf16 inputs (conv2c). 256 thr, 1 row. -------
__global__ __launch_bounds__(256, 4) void conv3x3_hilo_bf(
    const unsigned short* __restrict__ xhg, const unsigned short* __restrict__ xlg,
    int Cin, const unsigned short* __restrict__ wph, const unsigned short* __restrict__ wpl,
    const float* __restrict__ bn, float* __restrict__ out_f32)
{
    const int t   = threadIdx.x;
    const int w2  = t >> 6;
    const int xh  = w2 & 1;
    const int wy  = w2 >> 1;
    const int ln  = t & 63;
    const int l31 = ln & 31;
    const int g   = ln >> 5;
    const int y   = blockIdx.x;
    const int co0 = blockIdx.y << 6;
    const int b   = blockIdx.z;

    const int sr   = t >> 6;
    const int sx   = t & 63;
    const int sgy  = y - 1 + sr;
    const bool sv  = (t < 192) && ((unsigned)sgy < 64u);
    const int spid = sr * 66 + sx + 1;

    __shared__ __align__(16) unsigned short Xa[2][3168];
    __shared__ __align__(16) unsigned short Xb[2][3168];   // 25344 B

    for (int i = t; i < 792; i += 256) {
        uint4 z; z.x = 0; z.y = 0; z.z = 0; z.w = 0;
        ((uint4*)Xa)[i] = z;
        ((uint4*)Xb)[i] = z;
    }

    const int co = co0 + (wy << 5) + l31;
    const unsigned short* wHb = wph + (size_t)(g << 10) + ((size_t)co << 3);
    const unsigned short* wLb = wpl + (size_t)(g << 10) + ((size_t)co << 3);
    const unsigned short* hsrc = xhg + (((size_t)b * Cin) << 12) + (sgy << 6) + sx;
    const unsigned short* lsrc = xlg + (((size_t)b * Cin) << 12) + (sgy << 6) + sx;

    const f32x16 zero = {0,0,0,0,0,0,0,0,0,0,0,0,0,0,0,0};
    f32x16 acc = zero;

    unsigned short hv[16], lv[16];
    if (sv) {
#pragma unroll
        for (int c = 0; c < 16; c++) { hv[c] = hsrc[(size_t)c << 12]; lv[c] = lsrc[(size_t)c << 12]; }
    }
    __syncthreads();

    if (sv) {
        *(uint4*)&Xa[0][spid << 3]          = ((uint4*)hv)[0];
        *(uint4*)&Xa[0][1584 + (spid << 3)] = ((uint4*)hv)[1];
        *(uint4*)&Xb[0][spid << 3]          = ((uint4*)lv)[0];
        *(uint4*)&Xb[0][1584 + (spid << 3)] = ((uint4*)lv)[1];
    }

    const int nchunks = Cin >> 4;
    int cur = 0;
    for (int ch = 0; ch < nchunks; ++ch) {
        __syncthreads();
        const bool pf = (ch < nchunks - 1);
        if (pf && sv) {
#pragma unroll
            for (int c = 0; c < 16; c++) {
                hv[c] = hsrc[((size_t)(ch + 1) << 16) + ((size_t)c << 12)];
                lv[c] = lsrc[((size_t)(ch + 1) << 16) + ((size_t)c << 12)];
            }
        }
        const size_t wo = (size_t)ch * 18432;
#pragma unroll 3
        for (int tap = 0; tap < 9; ++tap) {
            const int dy = tap / 3, dx = tap - dy * 3;
            const int xi = (g ? 1584 : 0) + (((dy * 66) + (xh << 5) + l31 + dx) << 3);
            short8 ah  = *(const short8*)(wHb + wo + tap * 2048);
            short8 al  = *(const short8*)(wLb + wo + tap * 2048);
            short8 bh_ = *(const short8*)&Xa[cur][xi];
            short8 bl_ = *(const short8*)&Xb[cur][xi];
            acc = __builtin_amdgcn_mfma_f32_32x32x16_bf16(ah, bh_, acc, 0, 0, 0);
            acc = __builtin_amdgcn_mfma_f32_32x32x16_bf16(ah, bl_, acc, 0, 0, 0);
            acc = __builtin_amdgcn_mfma_f32_32x32x16_bf16(al, bh_, acc, 0, 0, 0);
        }
        if (pf && sv) {
            const int nb = cur ^ 1;
            *(uint4*)&Xa[nb][spid << 3]          = ((uint4*)hv)[0];
            *(uint4*)&Xa[nb][1584 + (spid << 3)] = ((uint4*)hv)[1];
            *(uint4*)&Xb[nb][spid << 3]          = ((uint4*)lv)[0];
            *(uint4*)&Xb[nb][1584 + (spid << 3)] = ((uint4*)lv)[1];
        }
        cur ^= 1;
    }

    const int x = (xh << 5) + l31;
#pragma unroll
    for (int r = 0; r < 16; r++) {
        int c2 = co0 + (wy << 5) + (r & 3) + ((r >> 2) << 3) + (g << 2);
        float v = fmaf(acc[r], bn[c2], bn[128 + c2]);
        v = v > 0.f ? v : 0.f;
        out_f32[(((size_t)b * 128 + c2) << 12) + (y << 6) + x] = v;
    }
}

// ---- CAM Gram via hi/lo MFMA, upper-triangle tiles + mirror write. --------
// grid (10, 8, 8): blockIdx.x -> (i0c, j0c) with j0c >= i0c.
__global__ __launch_bounds__(256) void cam_energy_mfma(
    const unsigned short* __restrict__ bh, const unsigned short* __restrict__ bl,
    float* __restrict__ egy_part)
{
    const int t   = threadIdx.x;
    const int w   = t >> 6;
    const int ln  = t & 63;
    const int l31 = ln & 31;
    const int g   = ln >> 5;
    const int bx  = blockIdx.x;
    int i0c, j0c;
    if (bx < 4)      { i0c = 0; j0c = bx; }
    else if (bx < 7) { i0c = 1; j0c = bx - 3; }
    else if (bx < 9) { i0c = 2; j0c = bx - 5; }
    else             { i0c = 3; j0c = 3; }
    const int i0  = i0c << 5;
    const int j0  = j0c << 5;
    const int nseg = blockIdx.y;
    const int b   = blockIdx.z;

    __shared__ float red[4][64][17];

    const f32x16 zero = {0,0,0,0,0,0,0,0,0,0,0,0,0,0,0,0};
    f32x16 acc = zero;
    const int nb = (nseg << 9) + (w << 7) + (g << 3);
    const size_t ri = ((size_t)b * 128 + i0 + l31) << 12;
    const size_t rj = ((size_t)b * 128 + j0 + l31) << 12;

#pragma unroll
    for (int c = 0; c < 8; c++) {
        const int n0 = nb + (c << 4);
        short8 ah  = *(const short8*)(bh + ri + n0);
        short8 al  = *(const short8*)(bl + ri + n0);
        short8 bhf = *(const short8*)(bh + rj + n0);
        short8 blf = *(const short8*)(bl + rj + n0);
        acc = __builtin_amdgcn_mfma_f32_32x32x16_bf16(ah, bhf, acc, 0, 0, 0);
        acc = __builtin_amdgcn_mfma_f32_32x32x16_bf16(ah, blf, acc, 0, 0, 0);
        acc = __builtin_amdgcn_mfma_f32_32x32x16_bf16(al, bhf, acc, 0, 0, 0);
    }
#pragma unroll
    for (int r = 0; r < 16; r++) red[w][ln][r] = acc[r];
    __syncthreads();

    const int lane = t & 63;
    const int rq   = t >> 6;
    float* base = egy_part + (((size_t)(nseg * 8 + b)) << 14);
#pragma unroll
    for (int e = 0; e < 4; e++) {
        const int reg = (rq << 2) + e;
        float v = red[0][lane][reg] + red[1][lane][reg]
                + red[2][lane][reg] + red[3][lane][reg];
        const int i = i0 + (reg & 3) + ((reg >> 2) << 3) + ((lane >> 5) << 2);
        const int j = j0 + (lane & 31);
        base[i * 128 + j] = v;
        if (i0c != j0c) base[j * 128 + i] = v;   // Gram symmetry mirror
    }
}

// ---- CAM softmax of (rowmax - e), fused 8-seg reduce. grid (8, 8) ---------
__global__ __launch_bounds__(256) void cam_softmax_fused(
    const float* __restrict__ egy_part, float* __restrict__ egy)
{
    const int b   = blockIdx.x;
    const int rg  = blockIdx.y;
    const int t   = threadIdx.x;
    const int row = (rg << 4) + (t >> 4);
    const int jg  = t & 15;

    float e[8];
#pragma unroll
    for (int jj = 0; jj < 8; jj++) e[jj] = 0.f;
    for (int seg = 0; seg < 8; seg++) {
        const float* p = egy_part + (((size_t)(seg * 8 + b)) << 14) + row * 128 + (jg << 3);
#pragma unroll
        for (int jj = 0; jj < 8; jj++) e[jj] += p[jj];
    }
    float mn = e[0];
#pragma unroll
    for (int jj = 1; jj < 8; jj++) mn = fminf(mn, e[jj]);
#pragma unroll
    for (int k = 1; k < 16; k <<= 1) mn = fminf(mn, __shfl_xor(mn, k));
    float s = 0.f;
#pragma unroll
    for (int jj = 0; jj < 8; jj++) { float p = __expf(mn - e[jj]); e[jj] = p; s += p; }
#pragma unroll
    for (int k = 1; k < 16; k <<= 1) s += __shfl_xor(s, k);
    const float inv = 1.f / s;
    float* orow = egy + ((size_t)b << 14) + row * 128 + (jg << 3);
#pragma unroll
    for (int jj = 0; jj < 8; jj++) orow[jj] = e[jj] * inv;
}

// ---- PAM Q/K producer ----
__global__ __launch_bounds__(256) void pam_qk_1x1(
    const float* __restrict__ A, const float* __restrict__ Wb, const float* __restrict__ bb,
    const float* __restrict__ Wc, const float* __restrict__ bc,
    unsigned short* __restrict__ qt, unsigned short* __restrict__ kt)
{
    __shared__ float wl[2 * 16 * 128];
    __shared__ float bl[32];
    const int t = threadIdx.x;
    const int n = (blockIdx.x << 8) + t;
    const int b = blockIdx.y;
    for (int idx = t; idx < 2048; idx += 256) { wl[idx] = Wb[idx]; wl[2048 + idx] = Wc[idx]; }
    if (t < 16) { bl[t] = bb[t]; bl[16 + t] = bc[t]; }
    __syncthreads();
    float ab[16], ac[16];
#pragma unroll
    for (int k = 0; k < 16; k++) { ab[k] = 0.f; ac[k] = 0.f; }
    for (int chn = 0; chn < 128; ++chn) {
        float a = A[(((size_t)b * 128 + chn) << 12) + n];
#pragma unroll
        for (int k = 0; k < 16; k++) {
            ab[k] = fmaf(wl[k * 128 + chn], a, ab[k]);
            ac[k] = fmaf(wl[2048 + k * 128 + chn], a, ac[k]);
        }
    }
    unsigned short uq[16], uk[16];
#pragma unroll
    for (int k = 0; k < 16; k++) {
        uq[k] = f2bf(ab[k] + bl[k]);
        uk[k] = f2bf(ac[k] + bl[16 + k]);
    }
    size_t row = (size_t)b * 4096 + n;
    ((uint4*)qt)[row * 2 + 0] = ((uint4*)uq)[0];
    ((uint4*)qt)[row * 2 + 1] = ((uint4*)uq)[1];
    ((uint4*)kt)[row * 2 + 0] = ((uint4*)uk)[0];
    ((uint4*)kt)[row * 2 + 1] = ((uint4*)uk)[1];
}

// ---- PAM V producer ----
__global__ __launch_bounds__(256) void pam_v_1x1(
    const float* __restrict__ A, const float* __restrict__ Wd, const float* __restrict__ bd,
    unsigned short* __restrict__ vb)
{
    __shared__ float wl[32 * 128];
    __shared__ float bl[32];
    const int t   = threadIdx.x;
    const int n   = (blockIdx.x << 8) + t;
    const int co0 = blockIdx.y << 5;
    const int b   = blockIdx.z;
    for (int idx = t; idx < 4096; idx += 256) {
        int c2 = idx >> 7, chv = idx & 127;
        wl[idx] = Wd[(co0 + c2) * 128 + chv];
    }
    if (t < 32) bl[t] = bd[co0 + t];
    __syncthreads();
    float acc[32];
#pragma unroll
    for (int k = 0; k < 32; k++) acc[k] = 0.f;
    for (int chn = 0; chn < 128; ++chn) {
        float a = A[(((size_t)b * 128 + chn) << 12) + n];
#pragma unroll
        for (int k = 0; k < 32; k++) acc[k] = fmaf(wl[k * 128 + chn], a, acc[k]);
    }
#pragma unroll
    for (int k = 0; k < 32; k++)
        vb[(((size_t)b * 128 + co0 + k) << 12) + n] = f2bf(acc[k] + bl[k]);
}

// ---- PAM attention, MFMA, ONLINE softmax, n0=64 Q-tile --------------------
// Each vfrag load feeds 2 PV MFMAs (n-groups 0/1). Pf/red double-buffered ->
// 2 barriers per m0 iteration. grid (64, 8), 256 thr.
__global__ __launch_bounds__(256) void pam_attn_mfma(
    const unsigned short* __restrict__ qt, const unsigned short* __restrict__ kt,
    const unsigned short* __restrict__ vb,
    const float* __restrict__ alpha, const float* __restrict__ Y,
    unsigned short* __restrict__ outb)
{
    const int t  = threadIdx.x;
    const int w  = t >> 6;
    const int L  = t & 63;
    const int ln = L & 31;
    const int g  = L >> 5;
    const int b  = blockIdx.y;
    const int n0 = blockIdx.x << 6;
    const int c0 = w << 5;

    __shared__ unsigned short Pf[2][16 * 512];   // 32 KB
    __shared__ float red[2][4][64];              // 2 KB
    __shared__ float redS[4][64];                // 1 KB

    const f32x16 zero = {0,0,0,0,0,0,0,0,0,0,0,0,0,0,0,0};
    short8 q0 = *(const short8*)(qt + (((size_t)b * 4096 + n0 + ln) << 4) + (g << 3));
    short8 q1 = *(const short8*)(qt + (((size_t)b * 4096 + n0 + 32 + ln) << 4) + (g << 3));
    const float al = alpha[0];

    f32x16 acc0 = zero, acc1 = zero;
    float rs0 = 0.f, rs1 = 0.f;
    float mold0 = -3.0e38f, mold1 = -3.0e38f;

    int par = 0;
    for (int m0 = 0; m0 < 4096; m0 += 128) {
        const int mq = m0 + (w << 5);
        short8 kfrag = *(const short8*)(kt + (((size_t)b * 4096 + mq + ln) << 4) + (g << 3));
        f32x16 s0 = __builtin_amdgcn_mfma_f32_32x32x16_bf16(kfrag, q0, zero, 0, 0, 0);
        f32x16 s1 = __builtin_amdgcn_mfma_f32_32x32x16_bf16(kfrag, q1, zero, 0, 0, 0);

        float lm0 = s0[0], lm1 = s1[0];
#pragma unroll
        for (int r = 1; r < 16; r++) { lm0 = fmaxf(lm0, s0[r]); lm1 = fmaxf(lm1, s1[r]); }
        lm0 = fmaxf(lm0, __shfl_xor(lm0, 32));
        lm1 = fmaxf(lm1, __shfl_xor(lm1, 32));
        if (L < 32) { red[par][w][L] = lm0; red[par][w][32 + L] = lm1; }
        __syncthreads();                                   // B1: red[par] ready
        const float mb0 = fmaxf(fmaxf(red[par][0][ln], red[par][1][ln]),
                                fmaxf(red[par][2][ln], red[par][3][ln]));
        const float mb1 = fmaxf(fmaxf(red[par][0][32 + ln], red[par][1][32 + ln]),
                                fmaxf(red[par][2][32 + ln], red[par][3][32 + ln]));
        const float mnew0 = fmaxf(mold0, mb0);
        const float mnew1 = fmaxf(mold1, mb1);
        const float fs0 = __expf(mold0 - mnew0);
        const float fs1 = __expf(mold1 - mnew1);
        mold0 = mnew0; mold1 = mnew1;
        rs0 *= fs0; rs1 *= fs1;
#pragma unroll
        for (int r = 0; r < 16; r++) { acc0[r] *= fs0; acc1[r] *= fs1; }

        // group 0
        {
            float p[16];
#pragma unroll
            for (int r = 0; r < 16; r++) { p[r] = __expf(s0[r] - mnew0); rs0 += p[r]; }
            float xx[16];
#pragma unroll
            for (int r = 0; r < 16; r++) xx[r] = __shfl_xor(p[r], 32);
            unsigned short f0[8], f1[8];
#pragma unroll
            for (int i = 0; i < 4; i++) {
                f0[i]     = f2bf(g ? xx[4 + i]  : p[i]);
                f0[4 + i] = f2bf(g ? p[4 + i]   : xx[i]);
                f1[i]     = f2bf(g ? xx[12 + i] : p[8 + i]);
                f1[4 + i] = f2bf(g ? p[12 + i]  : xx[8 + i]);
            }
            *(short8*)(&Pf[par][((w << 2) + g) * 512 + (ln << 3)])     = *(short8*)f0;
            *(short8*)(&Pf[par][((w << 2) + 2 + g) * 512 + (ln << 3)]) = *(short8*)f1;
        }
        // group 1
        {
            float p[16];
#pragma unroll
            for (int r = 0; r < 16; r++) { p[r] = __expf(s1[r] - mnew1); rs1 += p[r]; }
            float xx[16];
#pragma unroll
            for (int r = 0; r < 16; r++) xx[r] = __shfl_xor(p[r], 32);
            unsigned short f0[8], f1[8];
#pragma unroll
            for (int i = 0; i < 4; i++) {
                f0[i]     = f2bf(g ? xx[4 + i]  : p[i]);
                f0[4 + i] = f2bf(g ? p[4 + i]   : xx[i]);
                f1[i]     = f2bf(g ? xx[12 + i] : p[8 + i]);
                f1[4 + i] = f2bf(g ? p[12 + i]  : xx[8 + i]);
            }
            *(short8*)(&Pf[par][((w << 2) + g) * 512 + 256 + (ln << 3)])     = *(short8*)f0;
            *(short8*)(&Pf[par][((w << 2) + 2 + g) * 512 + 256 + (ln << 3)]) = *(short8*)f1;
        }
        __syncthreads();                                   // B2: Pf[par] ready

#pragma unroll
        for (int kk = 0; kk < 8; kk++) {
            short8 vfrag = *(const short8*)(vb + (((size_t)b * 128 + c0 + ln) << 12)
                                               + m0 + (kk << 4) + (g << 3));
            short8 pf0 = *(const short8*)(&Pf[par][((kk << 1) + g) * 512 + (ln << 3)]);
            short8 pf1 = *(const short8*)(&Pf[par][((kk << 1) + g) * 512 + 256 + (ln << 3)]);
            acc0 = __builtin_amdgcn_mfma_f32_32x32x16_bf16(vfrag, pf0, acc0, 0, 0, 0);
            acc1 = __builtin_amdgcn_mfma_f32_32x32x16_bf16(vfrag, pf1, acc1, 0, 0, 0);
        }
        par ^= 1;
    }

    rs0 += __shfl_xor(rs0, 32);
    rs1 += __shfl_xor(rs1, 32);
    if (L < 32) { redS[w][L] = rs0; redS[w][32 + L] = rs1; }
    __syncthreads();
    const float inv0 = 1.f / (redS[0][ln] + redS[1][ln] + redS[2][ln] + redS[3][ln]);
    const float inv1 = 1.f / (redS[0][32 + ln] + redS[1][32 + ln]
                            + redS[2][32 + ln] + redS[3][32 + ln]);
#pragma unroll
    for (int r = 0; r < 16; r++) {
        int c = c0 + (r & 3) + ((r >> 2) << 3) + (g << 2);
        size_t idx0 = (((size_t)b * 128 + c) << 12) + n0 + ln;
        outb[idx0]      = f2bf(fmaf(al, acc0[r] * inv0, Y[idx0]));
        outb[idx0 + 32] = f2bf(fmaf(al, acc1[r] * inv1, Y[idx0 + 32]));
    }
}

// ---- CAM feat: emits hi/lo bf16 directly (feeds conv2c) -------------------
__global__ __launch_bounds__(256) void cam_feat(
    const float* __restrict__ attn, const float* __restrict__ Bf,
    const float* __restrict__ beta, unsigned short* __restrict__ oh,
    unsigned short* __restrict__ ol)
{
    const int t  = threadIdx.x;
    const int n  = (blockIdx.x << 8) + t;
    const int c0 = blockIdx.y << 5;
    const int b  = blockIdx.z;
    __shared__ float al[32 * 128];
    for (int idx = t; idx < 4096; idx += 256)
        al[idx] = attn[(size_t)b * 16384 + (c0 + (idx >> 7)) * 128 + (idx & 127)];
    __syncthreads();
    float acc[32];
#pragma unroll
    for (int k = 0; k < 32; k++) acc[k] = 0.f;
    for (int d = 0; d < 128; ++d) {
        float v = Bf[(((size_t)b * 128 + d) << 12) + n];
#pragma unroll
        for (int k = 0; k < 32; k++) acc[k] = fmaf(al[k * 128 + d], v, acc[k]);
    }
    float be = beta[0];
#pragma unroll
    for (int k = 0; k < 32; k++) {
        size_t idx = (((size_t)b * 128 + c0 + k) << 12) + n;
        float v = fmaf(be, acc[k], Bf[idx]);
        unsigned short hi = f2bf(v);
        oh[idx] = hi;
        ol[idx] = f2bf(v - bf2f(hi));
    }
}

// ---- Final heads ----
__global__ __launch_bounds__(256) void heads(
    const float* __restrict__ FP, const float* __restrict__ FC,
    const float* __restrict__ Wout, const float* __restrict__ bout,
    const float* __restrict__ Wp3, const float* __restrict__ bp3,
    const float* __restrict__ Wc3, const float* __restrict__ bc3,
    float* __restrict__ out)
{
    const int t = threadIdx.x;
    const int n = (blockIdx.x << 8) + t;
    const int b = blockIdx.y;
    __shared__ float wl[3 * 19 * 128];
    __shared__ float bl[3 * 19];
    for (int idx = t; idx < 2432; idx += 256) {
        wl[idx]        = Wout[idx];
        wl[2432 + idx] = Wp3[idx];
        wl[4864 + idx] = Wc3[idx];
    }
    if (t < 19) { bl[t] = bout[t]; bl[19 + t] = bp3[t]; bl[38 + t] = bc3[t]; }
    __syncthreads();
    float am[19], ap[19], ac[19];
#pragma unroll
    for (int o = 0; o < 19; o++) { am[o] = 0.f; ap[o] = 0.f; ac[o] = 0.f; }
    for (int chn = 0; chn < 128; ++chn) {
        float pv = FP[(((size_t)b * 128 + chn) << 12) + n];
        float cv = FC[(((size_t)b * 128 + chn) << 12) + n];
        float fv = pv + cv;
#pragma unroll
        for (int o = 0; o < 19; o++) {
            am[o] = fmaf(wl[o * 128 + chn], fv, am[o]);
            ap[o] = fmaf(wl[2432 + o * 128 + chn], pv, ap[o]);
            ac[o] = fmaf(wl[4864 + o * 128 + chn], cv, ac[o]);
        }
    }
    const size_t OS = (size_t)8 * 19 * 4096;
#pragma unroll
    for (int o = 0; o < 19; o++) {
        size_t base = (((size_t)b * 19 + o) << 12) + n;
        out[base]          = 1.f / (1.f + __expf(-(am[o] + bl[o])));
        out[OS + base]     = 1.f / (1.f + __expf(-(ap[o] + bl[19 + o])));
        out[2 * OS + base] = 1.f / (1.f + __expf(-(ac[o] + bl[38 + o])));
    }
}

extern "C" void kernel_launch(void* const* d_in, const int* in_sizes, int n_in,
                              void* d_out, int out_size, void* d_ws, size_t ws_size,
                              hipStream_t stream)
{
    const float* x     = (const float*)d_in[0];
    const float* Wp1   = (const float*)d_in[1];
    const float* bnp1  = (const float*)d_in[2];
    const float* Wc1   = (const float*)d_in[3];
    const float* bnc1  = (const float*)d_in[4];
    const float* Wb    = (const float*)d_in[5];
    const float* bb    = (const float*)d_in[6];
    const float* Wc    = (const float*)d_in[7];
    const float* bcv   = (const float*)d_in[8];
    const float* Wd    = (const float*)d_in[9];
    const float* bd    = (const float*)d_in[10];
    const float* alpha = (const float*)d_in[11];
    const float* beta  = (const float*)d_in[12];
    const float* Wp2   = (const float*)d_in[13];
    const float* bnp2  = (const float*)d_in[14];
    const float* Wc2   = (const float*)d_in[15];
    const float* bnc2  = (const float*)d_in[16];
    const float* Wout  = (const float*)d_in[17];
    const float* bo    = (const float*)d_in[18];
    const float* Wp3   = (const float*)d_in[19];
    const float* bp3   = (const float*)d_in[20];
    const float* Wc3   = (const float*)d_in[21];
    const float* bc3   = (const float*)d_in[22];
    float* out = (float*)d_out;

    char* ws = (char*)d_ws;
    const size_t MB = 1u << 20;
    const size_t W1SZ = (size_t)32 * 18432 * 2;
    const size_t W2SZ = (size_t)8 * 18432 * 2;
    float*          bufA     = (float*)(ws);
    float*          bufB     = (float*)(ws + 16 * MB);
    unsigned short* vb       = (unsigned short*)(ws + 32 * MB);  // 8MB
    float*          egy_part = (float*)(ws + 40 * MB);           // 4MB
    float*          bufD     = (float*)(ws + 32 * MB);           // conv2p out (later)
    unsigned short* bh       = (unsigned short*)(ws + 48 * MB);  // 8MB
    unsigned short* blo      = (unsigned short*)(ws + 56 * MB);  // 8MB
    unsigned short* pam_bf   = (unsigned short*)(ws + 48 * MB);  // after Gram
    unsigned short* c2h      = (unsigned short*)(ws + 48 * MB);  // after conv2p
    unsigned short* c2l      = (unsigned short*)(ws + 56 * MB);
    unsigned short* qt       = (unsigned short*)(ws + 64 * MB);
    unsigned short* kt       = (unsigned short*)(ws + 65 * MB);
    float*          egy      = (float*)(ws + 66 * MB + (1u << 17));
    unsigned short* wp1      = (unsigned short*)(ws + 67 * MB);
    unsigned short* wc1h     = (unsigned short*)(ws + 67 * MB + W1SZ);
    unsigned short* wc1l     = (unsigned short*)(ws + 67 * MB + 2 * W1SZ);
    unsigned short* wp2      = (unsigned short*)(ws + 67 * MB + 3 * W1SZ);
    unsigned short* wc2h     = (unsigned short*)(ws + 67 * MB + 3 * W1SZ + W2SZ);
    unsigned short* wc2l     = (unsigned short*)(ws + 67 * MB + 3 * W1SZ + 2 * W2SZ);

    dim3 blk(256);
    const int n1 = 32 * 18432;
    const int n2 = 8 * 18432;
    wpack_kernel<<<dim3((n1 + 255) / 256), blk, 0, stream>>>(Wp1, wp1, 512, n1);
    wpack_kernel<<<dim3((n2 + 255) / 256), blk, 0, stream>>>(Wp2, wp2, 128, n2);
    wpack_split_kernel<<<dim3((n1 + 255) / 256), blk, 0, stream>>>(Wc1, wc1h, wc1l, 512, n1);
    wpack_split_kernel<<<dim3((n2 + 255) / 256), blk, 0, stream>>>(Wc2, wc2h, wc2l, 128, n2);

    // fused conv1p + conv1c (exact R9)
    conv3x3_merged<<<dim3(64, 2, 8), blk, 0, stream>>>(x, wp1, wc1h, wc1l, bnp1, bnc1,
                                                       bufA, bufB, bh, blo);
    // CAM Gram (triangle) + softmax
    cam_energy_mfma<<<dim3(10, 8, 8), blk, 0, stream>>>(bh, blo, egy_part);
    cam_softmax_fused<<<dim3(8, 8), blk, 0, stream>>>(egy_part, egy);
    // PAM
    pam_qk_1x1<<<dim3(16, 8), blk, 0, stream>>>(bufA, Wb, bb, Wc, bcv, qt, kt);
    pam_v_1x1<<<dim3(16, 4, 8), blk, 0, stream>>>(bufA, Wd, bd, vb);
    pam_attn_mfma<<<dim3(64, 8), blk, 0, stream>>>(qt, kt, vb, alpha, bufA, pam_bf);
    // conv2p (reads pam_bf, writes bufD over vb/egy_part which are now dead)
    conv3x3_bf<<<dim3(64, 2, 8), blk, 0, stream>>>(pam_bf, 128, wp2, bnp2, bufD);
    // CAM tail (c2h/c2l overwrite pam_bf region after conv2p consumed it)
    cam_feat<<<dim3(16, 4, 8), blk, 0, stream>>>(egy, bufB, beta, c2h, c2l);
    conv3x3_hilo_bf<<<dim3(64, 2, 8), blk, 0, stream>>>(c2h, c2l, 128, wc2h, wc2l, bnc2, bufA);
    // fusion + heads
    heads<<<dim3(16, 8), blk, 0, stream>>>(bufD, bufA, Wout, bo, Wp3, bp3, Wc3, bc3, out);
}